// Round 3
// baseline (4458.765 us; speedup 1.0000x reference)
//
#include <hip/hip_runtime.h>
#include <hip/hip_bf16.h>

#define B_ 2
#define S_ 2048
#define F_ 64
#define E_ 512
#define H_ 8
#define L_ 4
#define FF_ 2048
#define NTOK (B_*S_)
#define DH 64

typedef __attribute__((ext_vector_type(8))) short bf16x8;
typedef __attribute__((ext_vector_type(4))) float f32x4;
typedef unsigned short ushort_t;

__device__ __forceinline__ float b2f(unsigned short u) {
  union { unsigned int i; float f; } x; x.i = ((unsigned int)u) << 16; return x.f;
}
__device__ __forceinline__ unsigned short f2b(float f) {
  union { float f; unsigned int i; } x; x.f = f;
  unsigned int r = x.i + 0x7fffu + ((x.i >> 16) & 1u);
  return (unsigned short)(r >> 16);
}

// ---------------- generic f32 -> bf16 convert ----------------
__global__ __launch_bounds__(256) void f32_to_bf16(const float* __restrict__ in,
                                                   unsigned short* __restrict__ out, int n) {
  int i = blockIdx.x * blockDim.x + threadIdx.x;
  int stride = gridDim.x * blockDim.x;
  for (; i < n; i += stride) out[i] = f2b(in[i]);
}

// ---------------- embedding: x = seq @ W_emb + b + pos ----------------
__global__ __launch_bounds__(256)
void embed_kernel(const float* __restrict__ seq, const float* __restrict__ W,
                  const float* __restrict__ be, const float* __restrict__ pe,
                  float* __restrict__ xf, unsigned short* __restrict__ xb) {
  const int n = blockIdx.x;
  const int s = n & (S_ - 1);
  __shared__ float srow[F_];
  if (threadIdx.x < F_) srow[threadIdx.x] = seq[(size_t)n * F_ + threadIdx.x];
  __syncthreads();
  for (int e = threadIdx.x; e < E_; e += 256) {
    float acc = be[e] + pe[(size_t)s * E_ + e];
#pragma unroll 8
    for (int f = 0; f < F_; ++f) acc = fmaf(srow[f], W[(size_t)f * E_ + e], acc);
    xf[(size_t)n * E_ + e] = acc;
    xb[(size_t)n * E_ + e] = f2b(acc);
  }
}

// ---------------- bf16 MFMA GEMM, A[M,K] @ B[K,N] + bias ----------------
template<int BN, bool RELU>
__global__ __launch_bounds__(256)
void gemm_nn(const unsigned short* __restrict__ A, const unsigned short* __restrict__ Bw,
             const float* __restrict__ bias,
             float* __restrict__ Cf, unsigned short* __restrict__ Cb,
             int M, int N, int K) {
  constexpr int BM = 128, BK = 32;
  constexpr int FN = BN / 32;   // fragment cols per wave (2-wide wave grid)
  constexpr int WN = BN / 2;    // wave col extent
  __shared__ unsigned short Alds[BM][BK + 8];
  __shared__ unsigned short Blds[BN][BK + 8];
  const int t = threadIdx.x;
  const int wid = t >> 6, lane = t & 63;
  const int wr = wid >> 1, wc = wid & 1;
  const int rowBase = blockIdx.y * BM;
  const int colBase = blockIdx.x * BN;

  f32x4 acc[4][FN];
#pragma unroll
  for (int i = 0; i < 4; ++i)
#pragma unroll
    for (int j = 0; j < FN; ++j) acc[i][j] = (f32x4){0.f, 0.f, 0.f, 0.f};

  const int lr = lane & 15;
  const int kb = (lane >> 4) * 8;

  for (int k0 = 0; k0 < K; k0 += BK) {
    // stage A: BM x BK (8 bf16 per chunk, contiguous)
#pragma unroll
    for (int it = 0; it < (BM * BK / 8) / 256; ++it) {
      int idx = it * 256 + t;
      int r = idx >> 2;
      int c = (idx & 3) << 3;
      *(uint4*)&Alds[r][c] = *(const uint4*)&A[(size_t)(rowBase + r) * K + k0 + c];
    }
    // stage B transposed: global [BK][BN] -> Blds[n][k]
    constexpr int CPR = BN / 8;
    constexpr int BIT = (BK * BN / 8) / 256;
#pragma unroll
    for (int it = 0; it < BIT; ++it) {
      int idx = it * 256 + t;
      int kk = idx / CPR;
      int c = (idx % CPR) << 3;
      uint4 u = *(const uint4*)&Bw[(size_t)(k0 + kk) * N + colBase + c];
      const unsigned short* us = (const unsigned short*)&u;
#pragma unroll
      for (int j = 0; j < 8; ++j) Blds[c + j][kk] = us[j];
    }
    __syncthreads();

    bf16x8 af[4];
#pragma unroll
    for (int fm = 0; fm < 4; ++fm)
      af[fm] = *(const bf16x8*)&Alds[wr * 64 + fm * 16 + lr][kb];
#pragma unroll
    for (int fn = 0; fn < FN; ++fn) {
      bf16x8 bfr = *(const bf16x8*)&Blds[wc * WN + fn * 16 + lr][kb];
#pragma unroll
      for (int fm = 0; fm < 4; ++fm)
        acc[fm][fn] = __builtin_amdgcn_mfma_f32_16x16x32_bf16(af[fm], bfr, acc[fm][fn], 0, 0, 0);
    }
    __syncthreads();
  }

#pragma unroll
  for (int fm = 0; fm < 4; ++fm) {
#pragma unroll
    for (int fn = 0; fn < FN; ++fn) {
      int col = colBase + wc * WN + fn * 16 + (lane & 15);
      float bz = bias[col];
#pragma unroll
      for (int j = 0; j < 4; ++j) {
        int row = rowBase + wr * 64 + fm * 16 + (lane >> 4) * 4 + j;
        float v = acc[fm][fn][j] + bz;
        if (RELU) v = fmaxf(v, 0.f);
        size_t o = (size_t)row * N + col;
        if (Cf) Cf[o] = v;
        if (Cb) Cb[o] = f2b(v);
      }
    }
  }
}

// ---------------- fused flash-style attention (vector fp32) ----------------
__global__ __launch_bounds__(256)
void attn_kernel(const unsigned short* __restrict__ q, const unsigned short* __restrict__ k,
                 const unsigned short* __restrict__ v, const int* __restrict__ mask,
                 unsigned short* __restrict__ out) {
  __shared__ float Klds[64][65];
  __shared__ float Vlds[64][65];
  __shared__ float qlds[16][64];
  __shared__ float plds[4][64];
  const int t = threadIdx.x, wid = t >> 6, lane = t & 63;
  const int bid = blockIdx.x;
  const int qt = bid & 127;
  const int h = (bid >> 7) & 7;
  const int b = bid >> 10;
  const float scale = 0.04419417382415922f;  // 1/sqrt(512)

  for (int idx = t; idx < 16 * 64; idx += 256) {
    int r = idx >> 6, d = idx & 63;
    int n = b * S_ + qt * 16 + r;
    qlds[r][d] = b2f(q[(size_t)n * E_ + h * DH + d]) * scale;
  }
  __syncthreads();

  float m[4], ssum[4], o[4];
#pragma unroll
  for (int r = 0; r < 4; ++r) { m[r] = -INFINITY; ssum[r] = 0.f; o[r] = 0.f; }

  for (int kt = 0; kt < S_ / 64; ++kt) {
#pragma unroll
    for (int ii = 0; ii < 2; ++ii) {
      int idx = ii * 256 + t;
      int r = idx >> 3, c = (idx & 7) << 3;
      int n = b * S_ + kt * 64 + r;
      uint4 ku = *(const uint4*)&k[(size_t)n * E_ + h * DH + c];
      uint4 vu = *(const uint4*)&v[(size_t)n * E_ + h * DH + c];
      const unsigned short* ks = (const unsigned short*)&ku;
      const unsigned short* vs = (const unsigned short*)&vu;
#pragma unroll
      for (int j = 0; j < 8; ++j) { Klds[r][c + j] = b2f(ks[j]); Vlds[r][c + j] = b2f(vs[j]); }
    }
    __syncthreads();
    const bool validk = mask[b * S_ + kt * 64 + lane] != 0;
#pragma unroll 1
    for (int r = 0; r < 4; ++r) {
      int qr = wid * 4 + r;
      float s = 0.f;
#pragma unroll
      for (int d = 0; d < 64; ++d) s = fmaf(qlds[qr][d], Klds[lane][d], s);
      if (!validk) s = -1e20f;
      float mt = s;
#pragma unroll
      for (int off = 32; off > 0; off >>= 1) mt = fmaxf(mt, __shfl_xor(mt, off));
      float mn = fmaxf(m[r], mt);
      float p = __expf(s - mn);
      float pt = p;
#pragma unroll
      for (int off = 32; off > 0; off >>= 1) pt += __shfl_xor(pt, off);
      float fac = __expf(m[r] - mn);
      ssum[r] = ssum[r] * fac + pt;
      plds[wid][lane] = p;
      asm volatile("s_waitcnt lgkmcnt(0)" ::: "memory");
      float pv = 0.f;
#pragma unroll
      for (int kk = 0; kk < 64; ++kk) pv = fmaf(plds[wid][kk], Vlds[kk][lane], pv);
      o[r] = o[r] * fac + pv;
      m[r] = mn;
    }
    __syncthreads();
  }
#pragma unroll
  for (int r = 0; r < 4; ++r) {
    int n = b * S_ + qt * 16 + wid * 4 + r;
    out[(size_t)n * E_ + h * DH + lane] = f2b(o[r] / ssum[r]);
  }
}

// ---------------- fused residual + layernorm (+ bf16 recast) ----------------
__global__ __launch_bounds__(256)
void ln_kernel(const float* __restrict__ y, const float* __restrict__ xin,
               const float* __restrict__ g, const float* __restrict__ bb,
               float* __restrict__ xf, unsigned short* __restrict__ xb) {
  const int t = threadIdx.x, wid = t >> 6, lane = t & 63;
  const int row = blockIdx.x * 4 + wid;
  const float* yr = y + (size_t)row * E_;
  const float* xr = xin + (size_t)row * E_;
  float vals[8];
  float s = 0.f;
#pragma unroll
  for (int j = 0; j < 8; ++j) {
    float val = yr[lane * 8 + j] + xr[lane * 8 + j];
    vals[j] = val; s += val;
  }
#pragma unroll
  for (int off = 32; off > 0; off >>= 1) s += __shfl_xor(s, off);
  float mean = s * (1.f / 512.f);
  float vv = 0.f;
#pragma unroll
  for (int j = 0; j < 8; ++j) { float d = vals[j] - mean; vv += d * d; }
#pragma unroll
  for (int off = 32; off > 0; off >>= 1) vv += __shfl_xor(vv, off);
  float inv = rsqrtf(vv * (1.f / 512.f) + 1e-5f);
#pragma unroll
  for (int j = 0; j < 8; ++j) {
    int col = lane * 8 + j;
    float r = (vals[j] - mean) * inv * g[col] + bb[col];
    xf[(size_t)row * E_ + col] = r;
    xb[(size_t)row * E_ + col] = f2b(r);
  }
}

extern "C" void kernel_launch(void* const* d_in, const int* in_sizes, int n_in,
                              void* d_out, int out_size, void* d_ws, size_t ws_size,
                              hipStream_t stream) {
  const float* seq   = (const float*)d_in[0];
  const int*   mask  = (const int*)d_in[1];
  const float* W_emb = (const float*)d_in[2];
  const float* b_emb = (const float*)d_in[3];
  const float* pos   = (const float*)d_in[4];
  const float* Wq = (const float*)d_in[5];  const float* bq = (const float*)d_in[6];
  const float* Wk = (const float*)d_in[7];  const float* bk = (const float*)d_in[8];
  const float* Wv = (const float*)d_in[9];  const float* bv = (const float*)d_in[10];
  const float* Wo = (const float*)d_in[11]; const float* bo = (const float*)d_in[12];
  const float* ln1g = (const float*)d_in[13]; const float* ln1b = (const float*)d_in[14];
  const float* ln2g = (const float*)d_in[15]; const float* ln2b = (const float*)d_in[16];
  const float* W1 = (const float*)d_in[17]; const float* b1 = (const float*)d_in[18];
  const float* W2 = (const float*)d_in[19]; const float* b2 = (const float*)d_in[20];
  float* outp = (float*)d_out;

  char* w = (char*)d_ws;
  float*  x_f32    = (float*)w;           w += (size_t)NTOK * E_ * 4;
  float*  proj_f32 = (float*)w;           w += (size_t)NTOK * E_ * 4;
  unsigned short* x_b   = (unsigned short*)w; w += (size_t)NTOK * E_ * 2;
  unsigned short* q_b   = (unsigned short*)w; w += (size_t)NTOK * E_ * 2;
  unsigned short* k_b   = (unsigned short*)w; w += (size_t)NTOK * E_ * 2;
  unsigned short* v_b   = (unsigned short*)w; w += (size_t)NTOK * E_ * 2;
  unsigned short* at_b  = (unsigned short*)w; w += (size_t)NTOK * E_ * 2;
  unsigned short* ffn_b = (unsigned short*)w; w += (size_t)NTOK * FF_ * 2;
  unsigned short* Wq_b  = (unsigned short*)w; w += (size_t)L_ * E_ * E_ * 2;
  unsigned short* Wk_b  = (unsigned short*)w; w += (size_t)L_ * E_ * E_ * 2;
  unsigned short* Wv_b  = (unsigned short*)w; w += (size_t)L_ * E_ * E_ * 2;
  unsigned short* Wo_b  = (unsigned short*)w; w += (size_t)L_ * E_ * E_ * 2;
  unsigned short* W1_b  = (unsigned short*)w; w += (size_t)L_ * E_ * FF_ * 2;
  unsigned short* W2_b  = (unsigned short*)w; w += (size_t)L_ * FF_ * E_ * 2;

  const int ncv = L_ * E_ * E_;
  f32_to_bf16<<<1024, 256, 0, stream>>>(Wq, Wq_b, ncv);
  f32_to_bf16<<<1024, 256, 0, stream>>>(Wk, Wk_b, ncv);
  f32_to_bf16<<<1024, 256, 0, stream>>>(Wv, Wv_b, ncv);
  f32_to_bf16<<<1024, 256, 0, stream>>>(Wo, Wo_b, ncv);
  f32_to_bf16<<<1024, 256, 0, stream>>>(W1, W1_b, L_ * E_ * FF_);
  f32_to_bf16<<<1024, 256, 0, stream>>>(W2, W2_b, L_ * FF_ * E_);

  embed_kernel<<<NTOK, 256, 0, stream>>>(seq, W_emb, b_emb, pos, x_f32, x_b);

  dim3 g512(E_ / 64, NTOK / 128);
  dim3 gff(FF_ / 128, NTOK / 128);
  for (int i = 0; i < L_; ++i) {
    gemm_nn<64, false><<<g512, 256, 0, stream>>>(x_b, Wq_b + (size_t)i * E_ * E_, bq + i * E_,
                                                 nullptr, q_b, NTOK, E_, E_);
    gemm_nn<64, false><<<g512, 256, 0, stream>>>(x_b, Wk_b + (size_t)i * E_ * E_, bk + i * E_,
                                                 nullptr, k_b, NTOK, E_, E_);
    gemm_nn<64, false><<<g512, 256, 0, stream>>>(x_b, Wv_b + (size_t)i * E_ * E_, bv + i * E_,
                                                 nullptr, v_b, NTOK, E_, E_);
    attn_kernel<<<B_ * H_ * (S_ / 16), 256, 0, stream>>>(q_b, k_b, v_b, mask, at_b);
    gemm_nn<64, false><<<g512, 256, 0, stream>>>(at_b, Wo_b + (size_t)i * E_ * E_, bo + i * E_,
                                                 proj_f32, nullptr, NTOK, E_, E_);
    ln_kernel<<<NTOK / 4, 256, 0, stream>>>(proj_f32, x_f32, ln1g + i * E_, ln1b + i * E_,
                                            x_f32, x_b);
    gemm_nn<128, true><<<gff, 256, 0, stream>>>(x_b, W1_b + (size_t)i * E_ * FF_, b1 + i * FF_,
                                                nullptr, ffn_b, NTOK, FF_, E_);
    gemm_nn<64, false><<<g512, 256, 0, stream>>>(ffn_b, W2_b + (size_t)i * FF_ * E_, b2 + i * E_,
                                                 proj_f32, nullptr, NTOK, E_, FF_);
    float* xdst = (i == L_ - 1) ? outp : x_f32;
    ln_kernel<<<NTOK / 4, 256, 0, stream>>>(proj_f32, x_f32, ln2g + i * E_, ln2b + i * E_,
                                            xdst, x_b);
  }
}

// Round 4
// 1315.476 us; speedup vs baseline: 3.3895x; 3.3895x over previous
//
#include <hip/hip_runtime.h>
#include <hip/hip_bf16.h>

#define B_ 2
#define S_ 2048
#define F_ 64
#define E_ 512
#define H_ 8
#define L_ 4
#define FF_ 2048
#define NTOK (B_*S_)
#define DH 64

typedef __attribute__((ext_vector_type(8))) short bf16x8;
typedef __attribute__((ext_vector_type(4))) float f32x4;

__device__ __forceinline__ float b2f(unsigned short u) {
  union { unsigned int i; float f; } x; x.i = ((unsigned int)u) << 16; return x.f;
}
__device__ __forceinline__ unsigned short f2b(float f) {
  union { float f; unsigned int i; } x; x.f = f;
  unsigned int r = x.i + 0x7fffu + ((x.i >> 16) & 1u);
  return (unsigned short)(r >> 16);
}

// ---------------- generic f32 -> bf16 convert ----------------
__global__ __launch_bounds__(256) void f32_to_bf16(const float* __restrict__ in,
                                                   unsigned short* __restrict__ out, int n) {
  int i = blockIdx.x * blockDim.x + threadIdx.x;
  int stride = gridDim.x * blockDim.x;
  for (; i < n; i += stride) out[i] = f2b(in[i]);
}

// ---------------- embedding: x = seq @ W_emb + b + pos ----------------
__global__ __launch_bounds__(256)
void embed_kernel(const float* __restrict__ seq, const float* __restrict__ W,
                  const float* __restrict__ be, const float* __restrict__ pe,
                  float* __restrict__ xf, unsigned short* __restrict__ xb) {
  const int n = blockIdx.x;
  const int s = n & (S_ - 1);
  __shared__ float srow[F_];
  if (threadIdx.x < F_) srow[threadIdx.x] = seq[(size_t)n * F_ + threadIdx.x];
  __syncthreads();
  for (int e = threadIdx.x; e < E_; e += 256) {
    float acc = be[e] + pe[(size_t)s * E_ + e];
#pragma unroll 8
    for (int f = 0; f < F_; ++f) acc = fmaf(srow[f], W[(size_t)f * E_ + e], acc);
    xf[(size_t)n * E_ + e] = acc;
    xb[(size_t)n * E_ + e] = f2b(acc);
  }
}

// ---------------- bf16 MFMA GEMM, A[M,K] @ B[K,N] + bias ----------------
// Outputs (any may be null): Cf = f32 [M,N]; Cb = bf16 [M,N]; Ct = bf16 TRANSPOSED [N,M].
template<int BN, bool RELU>
__global__ __launch_bounds__(256)
void gemm_nn(const unsigned short* __restrict__ A, const unsigned short* __restrict__ Bw,
             const float* __restrict__ bias,
             float* __restrict__ Cf, unsigned short* __restrict__ Cb,
             unsigned short* __restrict__ Ct, float oscale,
             int M, int N, int K) {
  constexpr int BM = 128, BK = 32;
  constexpr int FN = BN / 32;   // fragment cols per wave (2-wide wave grid)
  constexpr int WN = BN / 2;    // wave col extent
  __shared__ unsigned short Alds[BM][BK + 8];
  __shared__ unsigned short Blds[BN][BK + 8];
  const int t = threadIdx.x;
  const int wid = t >> 6, lane = t & 63;
  const int wr = wid >> 1, wc = wid & 1;
  const int rowBase = blockIdx.y * BM;
  const int colBase = blockIdx.x * BN;

  f32x4 acc[4][FN];
#pragma unroll
  for (int i = 0; i < 4; ++i)
#pragma unroll
    for (int j = 0; j < FN; ++j) acc[i][j] = (f32x4){0.f, 0.f, 0.f, 0.f};

  const int lr = lane & 15;
  const int kb = (lane >> 4) * 8;

  for (int k0 = 0; k0 < K; k0 += BK) {
    // stage A: BM x BK (8 bf16 per chunk, contiguous)
#pragma unroll
    for (int it = 0; it < (BM * BK / 8) / 256; ++it) {
      int idx = it * 256 + t;
      int r = idx >> 2;
      int c = (idx & 3) << 3;
      *(uint4*)&Alds[r][c] = *(const uint4*)&A[(size_t)(rowBase + r) * K + k0 + c];
    }
    // stage B transposed: global [BK][BN] -> Blds[n][k]
    constexpr int CPR = BN / 8;
    constexpr int BIT = (BK * BN / 8) / 256;
#pragma unroll
    for (int it = 0; it < BIT; ++it) {
      int idx = it * 256 + t;
      int kk = idx / CPR;
      int c = (idx % CPR) << 3;
      uint4 u = *(const uint4*)&Bw[(size_t)(k0 + kk) * N + colBase + c];
      const unsigned short* us = (const unsigned short*)&u;
#pragma unroll
      for (int j = 0; j < 8; ++j) Blds[c + j][kk] = us[j];
    }
    __syncthreads();

    bf16x8 af[4];
#pragma unroll
    for (int fm = 0; fm < 4; ++fm)
      af[fm] = *(const bf16x8*)&Alds[wr * 64 + fm * 16 + lr][kb];
#pragma unroll
    for (int fn = 0; fn < FN; ++fn) {
      bf16x8 bfr = *(const bf16x8*)&Blds[wc * WN + fn * 16 + lr][kb];
#pragma unroll
      for (int fm = 0; fm < 4; ++fm)
        acc[fm][fn] = __builtin_amdgcn_mfma_f32_16x16x32_bf16(af[fm], bfr, acc[fm][fn], 0, 0, 0);
    }
    __syncthreads();
  }

#pragma unroll
  for (int fm = 0; fm < 4; ++fm) {
#pragma unroll
    for (int fn = 0; fn < FN; ++fn) {
      int col = colBase + wc * WN + fn * 16 + lr;
      float bz = bias[col];
      int row0 = rowBase + wr * 64 + fm * 16 + (lane >> 4) * 4;
      float vv[4];
#pragma unroll
      for (int j = 0; j < 4; ++j) {
        float v = (acc[fm][fn][j] + bz) * oscale;
        if (RELU) v = fmaxf(v, 0.f);
        vv[j] = v;
      }
      if (Cf) {
#pragma unroll
        for (int j = 0; j < 4; ++j) Cf[(size_t)(row0 + j) * N + col] = vv[j];
      }
      if (Cb) {
#pragma unroll
        for (int j = 0; j < 4; ++j) Cb[(size_t)(row0 + j) * N + col] = f2b(vv[j]);
      }
      if (Ct) {
        uint2 pk;
        pk.x = (unsigned)f2b(vv[0]) | ((unsigned)f2b(vv[1]) << 16);
        pk.y = (unsigned)f2b(vv[2]) | ((unsigned)f2b(vv[3]) << 16);
        *(uint2*)&Ct[(size_t)col * M + row0] = pk;
      }
    }
  }
}

// ---------------- MFMA flash attention ----------------
// Grid: B*H*(S/64) blocks of 256. Each wave owns 16 q rows. No __syncthreads.
// q: bf16 [NTOK][E] (pre-scaled by 1/sqrt(E) in the Q-GEMM epilogue)
// k: bf16 [NTOK][E]; vt: bf16 [E][NTOK] (V transposed); out: bf16 [NTOK][E]
__global__ __launch_bounds__(256)
void attn_mfma(const unsigned short* __restrict__ qg, const unsigned short* __restrict__ kg,
               const unsigned short* __restrict__ vt, const int* __restrict__ mask,
               unsigned short* __restrict__ outg) {
  __shared__ unsigned short plds[4][16][72];
  const int t = threadIdx.x;
  const int wid = t >> 6, lane = t & 63;
  const int g = lane >> 4, lr = lane & 15;
  const int bid = blockIdx.x;
  const int qt = bid & 31;
  const int h = (bid >> 5) & 7;
  const int b = bid >> 8;
  const int qrow = b * S_ + qt * 64 + wid * 16;
  const int hd = h * DH;

  // Q fragments: A[row=lr][k = ks*32 + g*8 + j], straight from global (b128)
  bf16x8 aq0, aq1;
  {
    const unsigned short* qp = qg + (size_t)(qrow + lr) * E_ + hd + g * 8;
    aq0 = *(const bf16x8*)qp;
    aq1 = *(const bf16x8*)(qp + 32);
  }

  f32x4 O[4];
#pragma unroll
  for (int dt = 0; dt < 4; ++dt) O[dt] = (f32x4){0.f, 0.f, 0.f, 0.f};
  float m[4], l[4];
#pragma unroll
  for (int j = 0; j < 4; ++j) { m[j] = -INFINITY; l[j] = 0.f; }

#pragma unroll 1
  for (int kt = 0; kt < S_ / 64; ++kt) {
    const int kb = kt * 64;
    // ---- S = Q K^T  (C layout: row q = g*4+j, col key = t16*16 + lr) ----
    const unsigned short* kp = kg + (size_t)(b * S_ + kb + lr) * E_ + hd + g * 8;
    f32x4 s[4];
#pragma unroll
    for (int t16 = 0; t16 < 4; ++t16) {
      bf16x8 bk0 = *(const bf16x8*)(kp + (size_t)t16 * 16 * E_);
      bf16x8 bk1 = *(const bf16x8*)(kp + (size_t)t16 * 16 * E_ + 32);
      f32x4 z = (f32x4){0.f, 0.f, 0.f, 0.f};
      z = __builtin_amdgcn_mfma_f32_16x16x32_bf16(aq0, bk0, z, 0, 0, 0);
      z = __builtin_amdgcn_mfma_f32_16x16x32_bf16(aq1, bk1, z, 0, 0, 0);
      s[t16] = z;
    }
    // ---- mask (key-column wise) ----
#pragma unroll
    for (int t16 = 0; t16 < 4; ++t16) {
      if (mask[b * S_ + kb + t16 * 16 + lr] == 0) {
#pragma unroll
        for (int j = 0; j < 4; ++j) s[t16][j] = -1e20f;
      }
    }
    // ---- online softmax (row-reduce across the 16-lane column group) ----
    float mn[4], fac[4];
#pragma unroll
    for (int j = 0; j < 4; ++j) {
      float v = fmaxf(fmaxf(s[0][j], s[1][j]), fmaxf(s[2][j], s[3][j]));
      v = fmaxf(v, __shfl_xor(v, 1));
      v = fmaxf(v, __shfl_xor(v, 2));
      v = fmaxf(v, __shfl_xor(v, 4));
      v = fmaxf(v, __shfl_xor(v, 8));
      mn[j] = fmaxf(m[j], v);
      fac[j] = __expf(m[j] - mn[j]);
      m[j] = mn[j];
    }
    float p[4][4];
#pragma unroll
    for (int t16 = 0; t16 < 4; ++t16)
#pragma unroll
      for (int j = 0; j < 4; ++j) p[t16][j] = __expf(s[t16][j] - mn[j]);
#pragma unroll
    for (int j = 0; j < 4; ++j) {
      float v = (p[0][j] + p[1][j]) + (p[2][j] + p[3][j]);
      v += __shfl_xor(v, 1);
      v += __shfl_xor(v, 2);
      v += __shfl_xor(v, 4);
      v += __shfl_xor(v, 8);
      l[j] = l[j] * fac[j] + v;
    }
#pragma unroll
    for (int dt = 0; dt < 4; ++dt)
#pragma unroll
      for (int j = 0; j < 4; ++j) O[dt][j] *= fac[j];
    // ---- P (C layout) -> LDS -> A-fragment layout ----
#pragma unroll
    for (int t16 = 0; t16 < 4; ++t16)
#pragma unroll
      for (int j = 0; j < 4; ++j)
        plds[wid][g * 4 + j][t16 * 16 + lr] = f2b(p[t16][j]);
    asm volatile("s_waitcnt lgkmcnt(0)" ::: "memory");
    __builtin_amdgcn_sched_barrier(0);
    bf16x8 pa0 = *(const bf16x8*)&plds[wid][lr][g * 8];
    bf16x8 pa1 = *(const bf16x8*)&plds[wid][lr][32 + g * 8];
    // ---- O += P V  (V fragments: contiguous keys from transposed V) ----
    const unsigned short* vp = vt + (size_t)(hd + lr) * NTOK + b * S_ + kb + g * 8;
#pragma unroll
    for (int dt = 0; dt < 4; ++dt) {
      bf16x8 bv0 = *(const bf16x8*)(vp + (size_t)dt * 16 * NTOK);
      bf16x8 bv1 = *(const bf16x8*)(vp + (size_t)dt * 16 * NTOK + 32);
      O[dt] = __builtin_amdgcn_mfma_f32_16x16x32_bf16(pa0, bv0, O[dt], 0, 0, 0);
      O[dt] = __builtin_amdgcn_mfma_f32_16x16x32_bf16(pa1, bv1, O[dt], 0, 0, 0);
    }
  }
  // ---- epilogue ----
  float inv[4];
#pragma unroll
  for (int j = 0; j < 4; ++j) inv[j] = 1.f / l[j];
#pragma unroll
  for (int dt = 0; dt < 4; ++dt)
#pragma unroll
    for (int j = 0; j < 4; ++j)
      outg[(size_t)(qrow + g * 4 + j) * E_ + hd + dt * 16 + lr] = f2b(O[dt][j] * inv[j]);
}

// ---------------- fused residual + layernorm (+ bf16 recast) ----------------
__global__ __launch_bounds__(256)
void ln_kernel(const float* __restrict__ y, const float* __restrict__ xin,
               const float* __restrict__ g, const float* __restrict__ bb,
               float* __restrict__ xf, unsigned short* __restrict__ xb) {
  const int t = threadIdx.x, wid = t >> 6, lane = t & 63;
  const int row = blockIdx.x * 4 + wid;
  const float* yr = y + (size_t)row * E_;
  const float* xr = xin + (size_t)row * E_;
  float vals[8];
  float s = 0.f;
#pragma unroll
  for (int j = 0; j < 8; ++j) {
    float val = yr[lane * 8 + j] + xr[lane * 8 + j];
    vals[j] = val; s += val;
  }
#pragma unroll
  for (int off = 32; off > 0; off >>= 1) s += __shfl_xor(s, off);
  float mean = s * (1.f / 512.f);
  float vv = 0.f;
#pragma unroll
  for (int j = 0; j < 8; ++j) { float d = vals[j] - mean; vv += d * d; }
#pragma unroll
  for (int off = 32; off > 0; off >>= 1) vv += __shfl_xor(vv, off);
  float inv = rsqrtf(vv * (1.f / 512.f) + 1e-5f);
#pragma unroll
  for (int j = 0; j < 8; ++j) {
    int col = lane * 8 + j;
    float r = (vals[j] - mean) * inv * g[col] + bb[col];
    xf[(size_t)row * E_ + col] = r;
    xb[(size_t)row * E_ + col] = f2b(r);
  }
}

extern "C" void kernel_launch(void* const* d_in, const int* in_sizes, int n_in,
                              void* d_out, int out_size, void* d_ws, size_t ws_size,
                              hipStream_t stream) {
  const float* seq   = (const float*)d_in[0];
  const int*   mask  = (const int*)d_in[1];
  const float* W_emb = (const float*)d_in[2];
  const float* b_emb = (const float*)d_in[3];
  const float* pos   = (const float*)d_in[4];
  const float* Wq = (const float*)d_in[5];  const float* bq = (const float*)d_in[6];
  const float* Wk = (const float*)d_in[7];  const float* bk = (const float*)d_in[8];
  const float* Wv = (const float*)d_in[9];  const float* bv = (const float*)d_in[10];
  const float* Wo = (const float*)d_in[11]; const float* bo = (const float*)d_in[12];
  const float* ln1g = (const float*)d_in[13]; const float* ln1b = (const float*)d_in[14];
  const float* ln2g = (const float*)d_in[15]; const float* ln2b = (const float*)d_in[16];
  const float* W1 = (const float*)d_in[17]; const float* b1 = (const float*)d_in[18];
  const float* W2 = (const float*)d_in[19]; const float* b2 = (const float*)d_in[20];
  float* outp = (float*)d_out;

  char* w = (char*)d_ws;
  float*  x_f32    = (float*)w;           w += (size_t)NTOK * E_ * 4;
  float*  proj_f32 = (float*)w;           w += (size_t)NTOK * E_ * 4;
  unsigned short* x_b   = (unsigned short*)w; w += (size_t)NTOK * E_ * 2;
  unsigned short* q_b   = (unsigned short*)w; w += (size_t)NTOK * E_ * 2;
  unsigned short* k_b   = (unsigned short*)w; w += (size_t)NTOK * E_ * 2;
  unsigned short* vt_b  = (unsigned short*)w; w += (size_t)NTOK * E_ * 2;
  unsigned short* at_b  = (unsigned short*)w; w += (size_t)NTOK * E_ * 2;
  unsigned short* ffn_b = (unsigned short*)w; w += (size_t)NTOK * FF_ * 2;
  unsigned short* Wq_b  = (unsigned short*)w; w += (size_t)L_ * E_ * E_ * 2;
  unsigned short* Wk_b  = (unsigned short*)w; w += (size_t)L_ * E_ * E_ * 2;
  unsigned short* Wv_b  = (unsigned short*)w; w += (size_t)L_ * E_ * E_ * 2;
  unsigned short* Wo_b  = (unsigned short*)w; w += (size_t)L_ * E_ * E_ * 2;
  unsigned short* W1_b  = (unsigned short*)w; w += (size_t)L_ * E_ * FF_ * 2;
  unsigned short* W2_b  = (unsigned short*)w; w += (size_t)L_ * FF_ * E_ * 2;

  const float qscale = 0.04419417382415922f;  // 1/sqrt(512)

  const int ncv = L_ * E_ * E_;
  f32_to_bf16<<<1024, 256, 0, stream>>>(Wq, Wq_b, ncv);
  f32_to_bf16<<<1024, 256, 0, stream>>>(Wk, Wk_b, ncv);
  f32_to_bf16<<<1024, 256, 0, stream>>>(Wv, Wv_b, ncv);
  f32_to_bf16<<<1024, 256, 0, stream>>>(Wo, Wo_b, ncv);
  f32_to_bf16<<<1024, 256, 0, stream>>>(W1, W1_b, L_ * E_ * FF_);
  f32_to_bf16<<<1024, 256, 0, stream>>>(W2, W2_b, L_ * FF_ * E_);

  embed_kernel<<<NTOK, 256, 0, stream>>>(seq, W_emb, b_emb, pos, x_f32, x_b);

  dim3 g512(E_ / 64, NTOK / 128);
  dim3 gff(FF_ / 128, NTOK / 128);
  for (int i = 0; i < L_; ++i) {
    gemm_nn<64, false><<<g512, 256, 0, stream>>>(x_b, Wq_b + (size_t)i * E_ * E_, bq + i * E_,
                                                 nullptr, q_b, nullptr, qscale, NTOK, E_, E_);
    gemm_nn<64, false><<<g512, 256, 0, stream>>>(x_b, Wk_b + (size_t)i * E_ * E_, bk + i * E_,
                                                 nullptr, k_b, nullptr, 1.f, NTOK, E_, E_);
    gemm_nn<64, false><<<g512, 256, 0, stream>>>(x_b, Wv_b + (size_t)i * E_ * E_, bv + i * E_,
                                                 nullptr, nullptr, vt_b, 1.f, NTOK, E_, E_);
    attn_mfma<<<B_ * H_ * (S_ / 64), 256, 0, stream>>>(q_b, k_b, vt_b, mask, at_b);
    gemm_nn<64, false><<<g512, 256, 0, stream>>>(at_b, Wo_b + (size_t)i * E_ * E_, bo + i * E_,
                                                 proj_f32, nullptr, nullptr, 1.f, NTOK, E_, E_);
    ln_kernel<<<NTOK / 4, 256, 0, stream>>>(proj_f32, x_f32, ln1g + i * E_, ln1b + i * E_,
                                            x_f32, x_b);
    gemm_nn<128, true><<<gff, 256, 0, stream>>>(x_b, W1_b + (size_t)i * E_ * FF_, b1 + i * FF_,
                                                nullptr, ffn_b, nullptr, 1.f, NTOK, FF_, E_);
    gemm_nn<64, false><<<g512, 256, 0, stream>>>(ffn_b, W2_b + (size_t)i * FF_ * E_, b2 + i * E_,
                                                 proj_f32, nullptr, nullptr, 1.f, NTOK, E_, FF_);
    float* xdst = (i == L_ - 1) ? outp : x_f32;
    ln_kernel<<<NTOK / 4, 256, 0, stream>>>(proj_f32, x_f32, ln2g + i * E_, ln2b + i * E_,
                                            xdst, x_b);
  }
}

// Round 5
// 1116.282 us; speedup vs baseline: 3.9943x; 1.1784x over previous
//
#include <hip/hip_runtime.h>
#include <hip/hip_bf16.h>

#define B_ 2
#define S_ 2048
#define F_ 64
#define E_ 512
#define H_ 8
#define L_ 4
#define FF_ 2048
#define NTOK (B_*S_)
#define DH 64

typedef __attribute__((ext_vector_type(8))) short bf16x8;
typedef __attribute__((ext_vector_type(4))) float f32x4;

__device__ __forceinline__ float b2f(unsigned short u) {
  union { unsigned int i; float f; } x; x.i = ((unsigned int)u) << 16; return x.f;
}
__device__ __forceinline__ unsigned short f2b(float f) {
  union { float f; unsigned int i; } x; x.f = f;
  unsigned int r = x.i + 0x7fffu + ((x.i >> 16) & 1u);
  return (unsigned short)(r >> 16);
}

// ---------------- tiled transpose + f32->bf16: W[z][K][N] -> Wt[z][N][K] ----------------
__global__ __launch_bounds__(256)
void transpose_bf16(const float* __restrict__ W, unsigned short* __restrict__ Wt,
                    int K, int N) {
  __shared__ unsigned short tile[32][33];
  const float* Wz = W + (size_t)blockIdx.z * K * N;
  unsigned short* Wtz = Wt + (size_t)blockIdx.z * K * N;
  const int n0 = blockIdx.x * 32, k0 = blockIdx.y * 32;
  const int tx = threadIdx.x & 31, ty = threadIdx.x >> 5;
#pragma unroll
  for (int i = 0; i < 4; ++i)
    tile[tx][ty + i * 8] = f2b(Wz[(size_t)(k0 + ty + i * 8) * N + n0 + tx]);
  __syncthreads();
#pragma unroll
  for (int i = 0; i < 4; ++i)
    Wtz[(size_t)(n0 + ty + i * 8) * K + k0 + tx] = tile[ty + i * 8][tx];
}

// ---------------- embedding: x = seq @ W_emb + b + pos ----------------
__global__ __launch_bounds__(256)
void embed_kernel(const float* __restrict__ seq, const float* __restrict__ W,
                  const float* __restrict__ be, const float* __restrict__ pe,
                  float* __restrict__ xf, unsigned short* __restrict__ xb) {
  const int n = blockIdx.x;
  const int s = n & (S_ - 1);
  __shared__ float srow[F_];
  if (threadIdx.x < F_) srow[threadIdx.x] = seq[(size_t)n * F_ + threadIdx.x];
  __syncthreads();
  for (int e = threadIdx.x; e < E_; e += 256) {
    float acc = be[e] + pe[(size_t)s * E_ + e];
#pragma unroll 8
    for (int f = 0; f < F_; ++f) acc = fmaf(srow[f], W[(size_t)f * E_ + e], acc);
    xf[(size_t)n * E_ + e] = acc;
    xb[(size_t)n * E_ + e] = f2b(acc);
  }
}

// ---------------- bf16 MFMA GEMM, A[M,K] @ Bt^T + bias (Bt is [N][K]) ----------------
// Outputs (any may be null): Cf = f32 [M,N]; Cb = bf16 [M,N]; Ct = bf16 TRANSPOSED [N,M].
template<int BN, bool RELU>
__global__ __launch_bounds__(256)
void gemm_tn(const unsigned short* __restrict__ A, const unsigned short* __restrict__ Bt,
             const float* __restrict__ bias,
             float* __restrict__ Cf, unsigned short* __restrict__ Cb,
             unsigned short* __restrict__ Ct, float oscale,
             int M, int N, int K) {
  constexpr int BM = 128, BK = 32;
  constexpr int FN = BN / 32;   // fragment cols per wave (2-wide wave grid)
  constexpr int WN = BN / 2;    // wave col extent
  __shared__ unsigned short Alds[BM][BK + 8];
  __shared__ unsigned short Blds[BN][BK + 8];
  const int t = threadIdx.x;
  const int wid = t >> 6, lane = t & 63;
  const int wr = wid >> 1, wc = wid & 1;
  const int rowBase = blockIdx.y * BM;
  const int colBase = blockIdx.x * BN;

  f32x4 acc[4][FN];
#pragma unroll
  for (int i = 0; i < 4; ++i)
#pragma unroll
    for (int j = 0; j < FN; ++j) acc[i][j] = (f32x4){0.f, 0.f, 0.f, 0.f};

  const int lr = lane & 15;
  const int kb = (lane >> 4) * 8;

  for (int k0 = 0; k0 < K; k0 += BK) {
#pragma unroll
    for (int it = 0; it < (BM * BK / 8) / 256; ++it) {
      int idx = it * 256 + t;
      int r = idx >> 2;
      int c = (idx & 3) << 3;
      *(uint4*)&Alds[r][c] = *(const uint4*)&A[(size_t)(rowBase + r) * K + k0 + c];
    }
#pragma unroll
    for (int it = 0; it < (BN * BK / 8) / 256; ++it) {
      int idx = it * 256 + t;
      int r = idx >> 2;
      int c = (idx & 3) << 3;
      *(uint4*)&Blds[r][c] = *(const uint4*)&Bt[(size_t)(colBase + r) * K + k0 + c];
    }
    __syncthreads();

    bf16x8 af[4];
#pragma unroll
    for (int fm = 0; fm < 4; ++fm)
      af[fm] = *(const bf16x8*)&Alds[wr * 64 + fm * 16 + lr][kb];
#pragma unroll
    for (int fn = 0; fn < FN; ++fn) {
      bf16x8 bfr = *(const bf16x8*)&Blds[wc * WN + fn * 16 + lr][kb];
#pragma unroll
      for (int fm = 0; fm < 4; ++fm)
        acc[fm][fn] = __builtin_amdgcn_mfma_f32_16x16x32_bf16(af[fm], bfr, acc[fm][fn], 0, 0, 0);
    }
    __syncthreads();
  }

#pragma unroll
  for (int fm = 0; fm < 4; ++fm) {
#pragma unroll
    for (int fn = 0; fn < FN; ++fn) {
      int col = colBase + wc * WN + fn * 16 + lr;
      float bz = bias[col];
      int row0 = rowBase + wr * 64 + fm * 16 + (lane >> 4) * 4;
      float vv[4];
#pragma unroll
      for (int j = 0; j < 4; ++j) {
        float v = (acc[fm][fn][j] + bz) * oscale;
        if (RELU) v = fmaxf(v, 0.f);
        vv[j] = v;
      }
      if (Cf) {
#pragma unroll
        for (int j = 0; j < 4; ++j) Cf[(size_t)(row0 + j) * N + col] = vv[j];
      }
      if (Cb) {
#pragma unroll
        for (int j = 0; j < 4; ++j) Cb[(size_t)(row0 + j) * N + col] = f2b(vv[j]);
      }
      if (Ct) {
        uint2 pk;
        pk.x = (unsigned)f2b(vv[0]) | ((unsigned)f2b(vv[1]) << 16);
        pk.y = (unsigned)f2b(vv[2]) | ((unsigned)f2b(vv[3]) << 16);
        *(uint2*)&Ct[(size_t)col * M + row0] = pk;
      }
    }
  }
}

// ---------------- MFMA flash attention, pipelined ----------------
// Grid: 512 blocks of 256, XCD-swizzled. Each wave owns 16 q rows. No __syncthreads.
// K tile double-buffered (prefetch next during softmax/PV); V loads issued before softmax.
#define ATTN_STEP(KC, KN, KT)                                                   \
  {                                                                             \
    const int kb_ = (KT) * 64;                                                  \
    f32x4 s_[4];                                                                \
    _Pragma("unroll") for (int t16 = 0; t16 < 4; ++t16) {                       \
      f32x4 z = (f32x4){0.f, 0.f, 0.f, 0.f};                                    \
      z = __builtin_amdgcn_mfma_f32_16x16x32_bf16(aq0, KC[2*t16], z, 0, 0, 0);  \
      z = __builtin_amdgcn_mfma_f32_16x16x32_bf16(aq1, KC[2*t16+1], z, 0, 0, 0);\
      s_[t16] = z;                                                              \
    }                                                                           \
    int mk_[4];                                                                 \
    _Pragma("unroll") for (int t16 = 0; t16 < 4; ++t16)                         \
      mk_[t16] = mask[mbase + kb_ + t16 * 16];                                  \
    bf16x8 vf_[8];                                                              \
    _Pragma("unroll") for (int dt = 0; dt < 4; ++dt) {                          \
      const unsigned short* p = vbase + (size_t)dt * 16 * NTOK + kb_;           \
      vf_[2*dt] = *(const bf16x8*)p;                                            \
      vf_[2*dt+1] = *(const bf16x8*)(p + 32);                                   \
    }                                                                           \
    {                                                                           \
      const int knt_ = ((KT) + 1) & 31;                                         \
      _Pragma("unroll") for (int t16 = 0; t16 < 4; ++t16) {                     \
        const unsigned short* p = kbase + (size_t)(knt_ * 64 + t16 * 16) * E_;  \
        KN[2*t16] = *(const bf16x8*)p;                                          \
        KN[2*t16+1] = *(const bf16x8*)(p + 32);                                 \
      }                                                                         \
    }                                                                           \
    _Pragma("unroll") for (int t16 = 0; t16 < 4; ++t16)                         \
      if (mk_[t16] == 0) {                                                      \
        _Pragma("unroll") for (int j = 0; j < 4; ++j) s_[t16][j] = -1e20f;      \
      }                                                                         \
    float mn_[4], fac_[4];                                                      \
    _Pragma("unroll") for (int j = 0; j < 4; ++j) {                             \
      float v = fmaxf(fmaxf(s_[0][j], s_[1][j]), fmaxf(s_[2][j], s_[3][j]));    \
      v = fmaxf(v, __shfl_xor(v, 1)); v = fmaxf(v, __shfl_xor(v, 2));           \
      v = fmaxf(v, __shfl_xor(v, 4)); v = fmaxf(v, __shfl_xor(v, 8));           \
      mn_[j] = fmaxf(m[j], v); fac_[j] = __expf(m[j] - mn_[j]); m[j] = mn_[j];  \
    }                                                                           \
    float p_[4][4];                                                             \
    _Pragma("unroll") for (int t16 = 0; t16 < 4; ++t16)                         \
      _Pragma("unroll") for (int j = 0; j < 4; ++j)                             \
        p_[t16][j] = __expf(s_[t16][j] - mn_[j]);                               \
    _Pragma("unroll") for (int t16 = 0; t16 < 4; ++t16)                         \
      _Pragma("unroll") for (int j = 0; j < 4; ++j)                             \
        plds[wid][g * 4 + j][t16 * 16 + lr] = f2b(p_[t16][j]);                  \
    _Pragma("unroll") for (int j = 0; j < 4; ++j) {                             \
      float v = (p_[0][j] + p_[1][j]) + (p_[2][j] + p_[3][j]);                  \
      v += __shfl_xor(v, 1); v += __shfl_xor(v, 2);                             \
      v += __shfl_xor(v, 4); v += __shfl_xor(v, 8);                             \
      l[j] = l[j] * fac_[j] + v;                                                \
    }                                                                           \
    _Pragma("unroll") for (int dt = 0; dt < 4; ++dt)                            \
      _Pragma("unroll") for (int j = 0; j < 4; ++j) O[dt][j] *= fac_[j];        \
    asm volatile("s_waitcnt lgkmcnt(0)" ::: "memory");                          \
    __builtin_amdgcn_sched_barrier(0);                                          \
    bf16x8 pa0 = *(const bf16x8*)&plds[wid][lr][g * 8];                         \
    bf16x8 pa1 = *(const bf16x8*)&plds[wid][lr][32 + g * 8];                    \
    _Pragma("unroll") for (int dt = 0; dt < 4; ++dt) {                          \
      O[dt] = __builtin_amdgcn_mfma_f32_16x16x32_bf16(pa0, vf_[2*dt], O[dt], 0, 0, 0);   \
      O[dt] = __builtin_amdgcn_mfma_f32_16x16x32_bf16(pa1, vf_[2*dt+1], O[dt], 0, 0, 0); \
    }                                                                           \
  }

__global__ __launch_bounds__(256, 2)
void attn_mfma(const unsigned short* __restrict__ qg, const unsigned short* __restrict__ kg,
               const unsigned short* __restrict__ vt, const int* __restrict__ mask,
               unsigned short* __restrict__ outg) {
  __shared__ unsigned short plds[4][16][72];
  const int t = threadIdx.x;
  const int wid = t >> 6, lane = t & 63;
  const int g = lane >> 4, lr = lane & 15;
  // XCD-aware bijective swizzle: blocks resident on one XCD share (b,h) -> K/V L2-resident
  const int bid = blockIdx.x;
  const int xcd = bid & 7, idx = bid >> 3;
  const int bh = xcd * 2 + (idx >> 5);   // 0..15
  const int qt = idx & 31;
  const int h = bh & 7, b = bh >> 3;
  const int bS = b * S_;
  const int qrow = bS + qt * 64 + wid * 16;
  const int hd = h * DH;

  // Q fragments: A[row=lr][k = ks*32 + g*8 + j], straight from global (b128)
  bf16x8 aq0, aq1;
  {
    const unsigned short* qp = qg + (size_t)(qrow + lr) * E_ + hd + g * 8;
    aq0 = *(const bf16x8*)qp;
    aq1 = *(const bf16x8*)(qp + 32);
  }

  f32x4 O[4];
#pragma unroll
  for (int dt = 0; dt < 4; ++dt) O[dt] = (f32x4){0.f, 0.f, 0.f, 0.f};
  float m[4], l[4];
#pragma unroll
  for (int j = 0; j < 4; ++j) { m[j] = -INFINITY; l[j] = 0.f; }

  const unsigned short* kbase = kg + (size_t)(bS + lr) * E_ + hd + g * 8;
  const unsigned short* vbase = vt + (size_t)(hd + lr) * NTOK + bS + g * 8;
  const int mbase = bS + lr;

  bf16x8 kA[8], kB[8];
  // preload K tile 0
#pragma unroll
  for (int t16 = 0; t16 < 4; ++t16) {
    const unsigned short* p = kbase + (size_t)(t16 * 16) * E_;
    kA[2*t16] = *(const bf16x8*)p;
    kA[2*t16+1] = *(const bf16x8*)(p + 32);
  }

#pragma unroll 1
  for (int kt = 0; kt < S_ / 64; kt += 2) {
    ATTN_STEP(kA, kB, kt)
    ATTN_STEP(kB, kA, kt + 1)
  }

  float inv[4];
#pragma unroll
  for (int j = 0; j < 4; ++j) inv[j] = 1.f / l[j];
#pragma unroll
  for (int dt = 0; dt < 4; ++dt)
#pragma unroll
    for (int j = 0; j < 4; ++j)
      outg[(size_t)(qrow + g * 4 + j) * E_ + hd + dt * 16 + lr] = f2b(O[dt][j] * inv[j]);
}

// ---------------- fused residual + layernorm (+ bf16 recast) ----------------
__global__ __launch_bounds__(256)
void ln_kernel(const float* __restrict__ y, const float* __restrict__ xin,
               const float* __restrict__ g, const float* __restrict__ bb,
               float* __restrict__ xf, unsigned short* __restrict__ xb) {
  const int t = threadIdx.x, wid = t >> 6, lane = t & 63;
  const int row = blockIdx.x * 4 + wid;
  const float* yr = y + (size_t)row * E_;
  const float* xr = xin + (size_t)row * E_;
  float vals[8];
  float s = 0.f;
#pragma unroll
  for (int j = 0; j < 8; ++j) {
    float val = yr[lane * 8 + j] + xr[lane * 8 + j];
    vals[j] = val; s += val;
  }
#pragma unroll
  for (int off = 32; off > 0; off >>= 1) s += __shfl_xor(s, off);
  float mean = s * (1.f / 512.f);
  float vv = 0.f;
#pragma unroll
  for (int j = 0; j < 8; ++j) { float d = vals[j] - mean; vv += d * d; }
#pragma unroll
  for (int off = 32; off > 0; off >>= 1) vv += __shfl_xor(vv, off);
  float inv = rsqrtf(vv * (1.f / 512.f) + 1e-5f);
#pragma unroll
  for (int j = 0; j < 8; ++j) {
    int col = lane * 8 + j;
    float r = (vals[j] - mean) * inv * g[col] + bb[col];
    xf[(size_t)row * E_ + col] = r;
    xb[(size_t)row * E_ + col] = f2b(r);
  }
}

extern "C" void kernel_launch(void* const* d_in, const int* in_sizes, int n_in,
                              void* d_out, int out_size, void* d_ws, size_t ws_size,
                              hipStream_t stream) {
  const float* seq   = (const float*)d_in[0];
  const int*   mask  = (const int*)d_in[1];
  const float* W_emb = (const float*)d_in[2];
  const float* b_emb = (const float*)d_in[3];
  const float* pos   = (const float*)d_in[4];
  const float* Wq = (const float*)d_in[5];  const float* bq = (const float*)d_in[6];
  const float* Wk = (const float*)d_in[7];  const float* bk = (const float*)d_in[8];
  const float* Wv = (const float*)d_in[9];  const float* bv = (const float*)d_in[10];
  const float* Wo = (const float*)d_in[11]; const float* bo = (const float*)d_in[12];
  const float* ln1g = (const float*)d_in[13]; const float* ln1b = (const float*)d_in[14];
  const float* ln2g = (const float*)d_in[15]; const float* ln2b = (const float*)d_in[16];
  const float* W1 = (const float*)d_in[17]; const float* b1 = (const float*)d_in[18];
  const float* W2 = (const float*)d_in[19]; const float* b2 = (const float*)d_in[20];
  float* outp = (float*)d_out;

  char* w = (char*)d_ws;
  float*  x_f32    = (float*)w;           w += (size_t)NTOK * E_ * 4;
  float*  proj_f32 = (float*)w;           w += (size_t)NTOK * E_ * 4;
  unsigned short* x_b   = (unsigned short*)w; w += (size_t)NTOK * E_ * 2;
  unsigned short* q_b   = (unsigned short*)w; w += (size_t)NTOK * E_ * 2;
  unsigned short* k_b   = (unsigned short*)w; w += (size_t)NTOK * E_ * 2;
  unsigned short* vt_b  = (unsigned short*)w; w += (size_t)NTOK * E_ * 2;
  unsigned short* at_b  = (unsigned short*)w; w += (size_t)NTOK * E_ * 2;
  unsigned short* ffn_b = (unsigned short*)w; w += (size_t)NTOK * FF_ * 2;
  unsigned short* Wq_b  = (unsigned short*)w; w += (size_t)L_ * E_ * E_ * 2;
  unsigned short* Wk_b  = (unsigned short*)w; w += (size_t)L_ * E_ * E_ * 2;
  unsigned short* Wv_b  = (unsigned short*)w; w += (size_t)L_ * E_ * E_ * 2;
  unsigned short* Wo_b  = (unsigned short*)w; w += (size_t)L_ * E_ * E_ * 2;
  unsigned short* W1_b  = (unsigned short*)w; w += (size_t)L_ * E_ * FF_ * 2;
  unsigned short* W2_b  = (unsigned short*)w; w += (size_t)L_ * FF_ * E_ * 2;

  const float qscale = 0.04419417382415922f;  // 1/sqrt(512)

  // weight transpose + convert: [L][K][N] f32 -> [L][N][K] bf16
  transpose_bf16<<<dim3(E_/32, E_/32, L_), 256, 0, stream>>>(Wq, Wq_b, E_, E_);
  transpose_bf16<<<dim3(E_/32, E_/32, L_), 256, 0, stream>>>(Wk, Wk_b, E_, E_);
  transpose_bf16<<<dim3(E_/32, E_/32, L_), 256, 0, stream>>>(Wv, Wv_b, E_, E_);
  transpose_bf16<<<dim3(E_/32, E_/32, L_), 256, 0, stream>>>(Wo, Wo_b, E_, E_);
  transpose_bf16<<<dim3(FF_/32, E_/32, L_), 256, 0, stream>>>(W1, W1_b, E_, FF_);
  transpose_bf16<<<dim3(E_/32, FF_/32, L_), 256, 0, stream>>>(W2, W2_b, FF_, E_);

  embed_kernel<<<NTOK, 256, 0, stream>>>(seq, W_emb, b_emb, pos, x_f32, x_b);

  dim3 g512(E_ / 64, NTOK / 128);
  dim3 gff(FF_ / 128, NTOK / 128);
  for (int i = 0; i < L_; ++i) {
    gemm_tn<64, false><<<g512, 256, 0, stream>>>(x_b, Wq_b + (size_t)i * E_ * E_, bq + i * E_,
                                                 nullptr, q_b, nullptr, qscale, NTOK, E_, E_);
    gemm_tn<64, false><<<g512, 256, 0, stream>>>(x_b, Wk_b + (size_t)i * E_ * E_, bk + i * E_,
                                                 nullptr, k_b, nullptr, 1.f, NTOK, E_, E_);
    gemm_tn<64, false><<<g512, 256, 0, stream>>>(x_b, Wv_b + (size_t)i * E_ * E_, bv + i * E_,
                                                 nullptr, nullptr, vt_b, 1.f, NTOK, E_, E_);
    attn_mfma<<<B_ * H_ * (S_ / 64), 256, 0, stream>>>(q_b, k_b, vt_b, mask, at_b);
    gemm_tn<64, false><<<g512, 256, 0, stream>>>(at_b, Wo_b + (size_t)i * E_ * E_, bo + i * E_,
                                                 proj_f32, nullptr, nullptr, 1.f, NTOK, E_, E_);
    ln_kernel<<<NTOK / 4, 256, 0, stream>>>(proj_f32, x_f32, ln1g + i * E_, ln1b + i * E_,
                                            x_f32, x_b);
    gemm_tn<128, true><<<gff, 256, 0, stream>>>(x_b, W1_b + (size_t)i * E_ * FF_, b1 + i * FF_,
                                                nullptr, ffn_b, nullptr, 1.f, NTOK, FF_, E_);
    gemm_tn<64, false><<<g512, 256, 0, stream>>>(ffn_b, W2_b + (size_t)i * FF_ * E_, b2 + i * E_,
                                                 proj_f32, nullptr, nullptr, 1.f, NTOK, E_, FF_);
    float* xdst = (i == L_ - 1) ? outp : x_f32;
    ln_kernel<<<NTOK / 4, 256, 0, stream>>>(proj_f32, x_f32, ln2g + i * E_, ln2b + i * E_,
                                            xdst, x_b);
  }
}

// Round 7
// 1042.338 us; speedup vs baseline: 4.2777x; 1.0709x over previous
//
#include <hip/hip_runtime.h>
#include <hip/hip_bf16.h>

#define B_ 2
#define S_ 2048
#define F_ 64
#define E_ 512
#define H_ 8
#define L_ 4
#define FF_ 2048
#define NTOK (B_*S_)
#define DH 64

typedef __attribute__((ext_vector_type(8))) short bf16x8;
typedef __attribute__((ext_vector_type(4))) float f32x4;

__device__ __forceinline__ float b2f(unsigned short u) {
  union { unsigned int i; float f; } x; x.i = ((unsigned int)u) << 16; return x.f;
}
__device__ __forceinline__ unsigned short f2b(float f) {
  union { float f; unsigned int i; } x; x.f = f;
  unsigned int r = x.i + 0x7fffu + ((x.i >> 16) & 1u);
  return (unsigned short)(r >> 16);
}

// ---------------- tiled transpose + f32->bf16 (+scale): W[z][K][N] -> Wt[z][N][K] ----------------
__global__ __launch_bounds__(256)
void transpose_bf16(const float* __restrict__ W, unsigned short* __restrict__ Wt,
                    int K, int N, size_t zstride, float scale) {
  __shared__ unsigned short tile[32][33];
  const float* Wz = W + (size_t)blockIdx.z * K * N;
  unsigned short* Wtz = Wt + (size_t)blockIdx.z * zstride;
  const int n0 = blockIdx.x * 32, k0 = blockIdx.y * 32;
  const int tx = threadIdx.x & 31, ty = threadIdx.x >> 5;
#pragma unroll
  for (int i = 0; i < 4; ++i)
    tile[tx][ty + i * 8] = f2b(Wz[(size_t)(k0 + ty + i * 8) * N + n0 + tx] * scale);
  __syncthreads();
#pragma unroll
  for (int i = 0; i < 4; ++i)
    Wtz[(size_t)(n0 + ty + i * 8) * K + k0 + tx] = tile[ty + i * 8][tx];
}

// ---------------- concat qkv bias (qscale folded into q part) ----------------
__global__ __launch_bounds__(256)
void build_bqkv(const float* __restrict__ bq, const float* __restrict__ bk,
                const float* __restrict__ bv, float* __restrict__ out, float qs) {
  int i = blockIdx.x * 256 + threadIdx.x;
  if (i >= L_ * 1536) return;
  int l = i / 1536, c = i - l * 1536;
  float v;
  if (c < 512) v = bq[l * 512 + c] * qs;
  else if (c < 1024) v = bk[l * 512 + c - 512];
  else v = bv[l * 512 + c - 1024];
  out[i] = v;
}

// ---------------- embedding: x = seq @ W_emb + b + pos ----------------
__global__ __launch_bounds__(256)
void embed_kernel(const float* __restrict__ seq, const float* __restrict__ W,
                  const float* __restrict__ be, const float* __restrict__ pe,
                  float* __restrict__ xf, unsigned short* __restrict__ xb) {
  const int n = blockIdx.x;
  const int s = n & (S_ - 1);
  __shared__ float srow[F_];
  if (threadIdx.x < F_) srow[threadIdx.x] = seq[(size_t)n * F_ + threadIdx.x];
  __syncthreads();
  for (int e = threadIdx.x; e < E_; e += 256) {
    float acc = be[e] + pe[(size_t)s * E_ + e];
#pragma unroll 8
    for (int f = 0; f < F_; ++f) acc = fmaf(srow[f], W[(size_t)f * E_ + e], acc);
    xf[(size_t)n * E_ + e] = acc;
    xb[(size_t)n * E_ + e] = f2b(acc);
  }
}

// ---------------- bf16 MFMA GEMM, A[M,K] @ Bt^T + bias (Bt is [N][K]) ----------------
// MODE 0: Cf (f32), Cb (bf16), Ct (bf16 transposed) — any may be null.
// MODE 1 (fused QKV, N=1536): col<512 -> Cb (q), col<1024 -> Cb2 (k), else Ct (v transposed).
template<int BN, bool RELU, int MODE>
__global__ __launch_bounds__(256)
void gemm_tn(const unsigned short* __restrict__ A, const unsigned short* __restrict__ Bt,
             const float* __restrict__ bias,
             float* __restrict__ Cf, unsigned short* __restrict__ Cb,
             unsigned short* __restrict__ Cb2, unsigned short* __restrict__ Ct,
             int M, int N, int K) {
  constexpr int BM = 128, BK = 32;
  constexpr int FN = BN / 32;   // fragment cols per wave (2-wide wave grid)
  constexpr int WN = BN / 2;    // wave col extent
  __shared__ unsigned short Alds[BM][BK + 8];
  __shared__ unsigned short Blds[BN][BK + 8];
  const int t = threadIdx.x;
  const int wid = t >> 6, lane = t & 63;
  const int wr = wid >> 1, wc = wid & 1;
  const int rowBase = blockIdx.y * BM;
  const int colBase = blockIdx.x * BN;

  f32x4 acc[4][FN];
#pragma unroll
  for (int i = 0; i < 4; ++i)
#pragma unroll
    for (int j = 0; j < FN; ++j) acc[i][j] = (f32x4){0.f, 0.f, 0.f, 0.f};

  const int lr = lane & 15;
  const int kb = (lane >> 4) * 8;

  for (int k0 = 0; k0 < K; k0 += BK) {
#pragma unroll
    for (int it = 0; it < (BM * BK / 8) / 256; ++it) {
      int idx = it * 256 + t;
      int r = idx >> 2;
      int c = (idx & 3) << 3;
      *(uint4*)&Alds[r][c] = *(const uint4*)&A[(size_t)(rowBase + r) * K + k0 + c];
    }
#pragma unroll
    for (int it = 0; it < (BN * BK / 8) / 256; ++it) {
      int idx = it * 256 + t;
      int r = idx >> 2;
      int c = (idx & 3) << 3;
      *(uint4*)&Blds[r][c] = *(const uint4*)&Bt[(size_t)(colBase + r) * K + k0 + c];
    }
    __syncthreads();

    bf16x8 af[4];
#pragma unroll
    for (int fm = 0; fm < 4; ++fm)
      af[fm] = *(const bf16x8*)&Alds[wr * 64 + fm * 16 + lr][kb];
#pragma unroll
    for (int fn = 0; fn < FN; ++fn) {
      bf16x8 bfr = *(const bf16x8*)&Blds[wc * WN + fn * 16 + lr][kb];
#pragma unroll
      for (int fm = 0; fm < 4; ++fm)
        acc[fm][fn] = __builtin_amdgcn_mfma_f32_16x16x32_bf16(af[fm], bfr, acc[fm][fn], 0, 0, 0);
    }
    __syncthreads();
  }

#pragma unroll
  for (int fm = 0; fm < 4; ++fm) {
#pragma unroll
    for (int fn = 0; fn < FN; ++fn) {
      int col = colBase + wc * WN + fn * 16 + lr;
      float bz = bias[col];
      int row0 = rowBase + wr * 64 + fm * 16 + (lane >> 4) * 4;
      float vv[4];
#pragma unroll
      for (int j = 0; j < 4; ++j) {
        float v = acc[fm][fn][j] + bz;
        if (RELU) v = fmaxf(v, 0.f);
        vv[j] = v;
      }
      if (MODE == 1) {
        int sel = col >> 9, lcol = col & 511;
        if (sel == 0) {
#pragma unroll
          for (int j = 0; j < 4; ++j) Cb[(size_t)(row0 + j) * E_ + lcol] = f2b(vv[j]);
        } else if (sel == 1) {
#pragma unroll
          for (int j = 0; j < 4; ++j) Cb2[(size_t)(row0 + j) * E_ + lcol] = f2b(vv[j]);
        } else {
          uint2 pk;
          pk.x = (unsigned)f2b(vv[0]) | ((unsigned)f2b(vv[1]) << 16);
          pk.y = (unsigned)f2b(vv[2]) | ((unsigned)f2b(vv[3]) << 16);
          *(uint2*)&Ct[(size_t)lcol * M + row0] = pk;
        }
      } else {
        if (Cf) {
#pragma unroll
          for (int j = 0; j < 4; ++j) Cf[(size_t)(row0 + j) * N + col] = vv[j];
        }
        if (Cb) {
#pragma unroll
          for (int j = 0; j < 4; ++j) Cb[(size_t)(row0 + j) * N + col] = f2b(vv[j]);
        }
        if (Ct) {
          uint2 pk;
          pk.x = (unsigned)f2b(vv[0]) | ((unsigned)f2b(vv[1]) << 16);
          pk.y = (unsigned)f2b(vv[2]) | ((unsigned)f2b(vv[3]) << 16);
          *(uint2*)&Ct[(size_t)col * M + row0] = pk;
        }
      }
    }
  }
}

// ---------------- MFMA flash attention, fixed-max softmax, K+V reg double-buffer ----------------
// softmax is scale-invariant => use fixed max 0: P = exp(s) (clamped), l = sum(P) reduced
// once in the epilogue. No shuffles, no rescale in the loop. mask==0 -> s=-1e20 -> P=0.
#define ATTN_STEP(KC, KN, VC, VN, KT)                                           \
  {                                                                             \
    const int kb_ = (KT) * 64;                                                  \
    const int knt_ = (((KT) + 1) & 31) * 64;                                    \
    _Pragma("unroll") for (int t16 = 0; t16 < 4; ++t16) {                       \
      const unsigned short* p = kbase + (size_t)(knt_ + t16 * 16) * E_;         \
      KN[2*t16]   = *(const bf16x8*)p;                                          \
      KN[2*t16+1] = *(const bf16x8*)(p + 32);                                   \
    }                                                                           \
    _Pragma("unroll") for (int dt = 0; dt < 4; ++dt) {                          \
      const unsigned short* p = vbase + (size_t)dt * 16 * NTOK + knt_;          \
      VN[2*dt]   = *(const bf16x8*)p;                                           \
      VN[2*dt+1] = *(const bf16x8*)(p + 32);                                    \
    }                                                                           \
    int mk_[4];                                                                 \
    _Pragma("unroll") for (int t16 = 0; t16 < 4; ++t16)                         \
      mk_[t16] = mask[mbase + kb_ + t16 * 16];                                  \
    f32x4 s_[4];                                                                \
    _Pragma("unroll") for (int t16 = 0; t16 < 4; ++t16) {                       \
      f32x4 z = (f32x4){0.f, 0.f, 0.f, 0.f};                                    \
      z = __builtin_amdgcn_mfma_f32_16x16x32_bf16(aq0, KC[2*t16], z, 0, 0, 0);  \
      z = __builtin_amdgcn_mfma_f32_16x16x32_bf16(aq1, KC[2*t16+1], z, 0, 0, 0);\
      s_[t16] = z;                                                              \
    }                                                                           \
    float p_[4][4];                                                             \
    _Pragma("unroll") for (int t16 = 0; t16 < 4; ++t16)                         \
      _Pragma("unroll") for (int j = 0; j < 4; ++j)                             \
        p_[t16][j] = (mk_[t16] == 0) ? 0.f : __expf(fminf(s_[t16][j], 45.f));   \
    _Pragma("unroll") for (int j = 0; j < 4; ++j)                               \
      lp[j] += (p_[0][j] + p_[1][j]) + (p_[2][j] + p_[3][j]);                   \
    _Pragma("unroll") for (int t16 = 0; t16 < 4; ++t16)                         \
      _Pragma("unroll") for (int j = 0; j < 4; ++j)                             \
        plds[wid][g * 4 + j][t16 * 16 + lr] = f2b(p_[t16][j]);                  \
    asm volatile("s_waitcnt lgkmcnt(0)" ::: "memory");                          \
    __builtin_amdgcn_sched_barrier(0);                                          \
    bf16x8 pa0 = *(const bf16x8*)&plds[wid][lr][g * 8];                         \
    bf16x8 pa1 = *(const bf16x8*)&plds[wid][lr][32 + g * 8];                    \
    _Pragma("unroll") for (int dt = 0; dt < 4; ++dt) {                          \
      O[dt] = __builtin_amdgcn_mfma_f32_16x16x32_bf16(pa0, VC[2*dt], O[dt], 0, 0, 0);   \
      O[dt] = __builtin_amdgcn_mfma_f32_16x16x32_bf16(pa1, VC[2*dt+1], O[dt], 0, 0, 0); \
    }                                                                           \
  }

__global__ __launch_bounds__(256, 2)
void attn_mfma(const unsigned short* __restrict__ qg, const unsigned short* __restrict__ kg,
               const unsigned short* __restrict__ vt, const int* __restrict__ mask,
               unsigned short* __restrict__ outg) {
  __shared__ unsigned short plds[4][16][72];
  const int t = threadIdx.x;
  const int wid = t >> 6, lane = t & 63;
  const int g = lane >> 4, lr = lane & 15;
  // XCD-aware bijective swizzle: blocks resident on one XCD share (b,h) -> K/V L2-resident
  const int bid = blockIdx.x;
  const int xcd = bid & 7, idx = bid >> 3;
  const int bh = xcd * 2 + (idx >> 5);   // 0..15
  const int qt = idx & 31;
  const int h = bh & 7, b = bh >> 3;
  const int bS = b * S_;
  const int qrow = bS + qt * 64 + wid * 16;
  const int hd = h * DH;

  bf16x8 aq0, aq1;
  {
    const unsigned short* qp = qg + (size_t)(qrow + lr) * E_ + hd + g * 8;
    aq0 = *(const bf16x8*)qp;
    aq1 = *(const bf16x8*)(qp + 32);
  }

  f32x4 O[4];
#pragma unroll
  for (int dt = 0; dt < 4; ++dt) O[dt] = (f32x4){0.f, 0.f, 0.f, 0.f};
  float lp[4] = {0.f, 0.f, 0.f, 0.f};

  const unsigned short* kbase = kg + (size_t)(bS + lr) * E_ + hd + g * 8;
  const unsigned short* vbase = vt + (size_t)(hd + lr) * NTOK + bS + g * 8;
  const int mbase = bS + lr;

  bf16x8 kA[8], kB[8], vA[8], vB[8];
#pragma unroll
  for (int t16 = 0; t16 < 4; ++t16) {
    const unsigned short* p = kbase + (size_t)(t16 * 16) * E_;
    kA[2*t16] = *(const bf16x8*)p;
    kA[2*t16+1] = *(const bf16x8*)(p + 32);
  }
#pragma unroll
  for (int dt = 0; dt < 4; ++dt) {
    const unsigned short* p = vbase + (size_t)dt * 16 * NTOK;
    vA[2*dt] = *(const bf16x8*)p;
    vA[2*dt+1] = *(const bf16x8*)(p + 32);
  }

#pragma unroll 1
  for (int kt = 0; kt < S_ / 64; kt += 2) {
    ATTN_STEP(kA, kB, vA, vB, kt)
    ATTN_STEP(kB, kA, vB, vA, kt + 1)
  }

  // epilogue: reduce l across the 16-lane column group, then normalize
#pragma unroll
  for (int j = 0; j < 4; ++j) {
    float v = lp[j];
    v += __shfl_xor(v, 1);
    v += __shfl_xor(v, 2);
    v += __shfl_xor(v, 4);
    v += __shfl_xor(v, 8);
    lp[j] = 1.f / v;
  }
#pragma unroll
  for (int dt = 0; dt < 4; ++dt)
#pragma unroll
    for (int j = 0; j < 4; ++j)
      outg[(size_t)(qrow + g * 4 + j) * E_ + hd + dt * 16 + lr] = f2b(O[dt][j] * lp[j]);
}

// ---------------- fused residual + layernorm (+ bf16 recast) ----------------
__global__ __launch_bounds__(256)
void ln_kernel(const float* __restrict__ y, const float* __restrict__ xin,
               const float* __restrict__ g, const float* __restrict__ bb,
               float* __restrict__ xf, unsigned short* __restrict__ xb) {
  const int t = threadIdx.x, wid = t >> 6, lane = t & 63;
  const int row = blockIdx.x * 4 + wid;
  const float* yr = y + (size_t)row * E_;
  const float* xr = xin + (size_t)row * E_;
  float vals[8];
  float s = 0.f;
#pragma unroll
  for (int j = 0; j < 8; ++j) {
    float val = yr[lane * 8 + j] + xr[lane * 8 + j];
    vals[j] = val; s += val;
  }
#pragma unroll
  for (int off = 32; off > 0; off >>= 1) s += __shfl_xor(s, off);
  float mean = s * (1.f / 512.f);
  float vv = 0.f;
#pragma unroll
  for (int j = 0; j < 8; ++j) { float d = vals[j] - mean; vv += d * d; }
#pragma unroll
  for (int off = 32; off > 0; off >>= 1) vv += __shfl_xor(vv, off);
  float inv = rsqrtf(vv * (1.f / 512.f) + 1e-5f);
#pragma unroll
  for (int j = 0; j < 8; ++j) {
    int col = lane * 8 + j;
    float r = (vals[j] - mean) * inv * g[col] + bb[col];
    xf[(size_t)row * E_ + col] = r;
    xb[(size_t)row * E_ + col] = f2b(r);
  }
}

extern "C" void kernel_launch(void* const* d_in, const int* in_sizes, int n_in,
                              void* d_out, int out_size, void* d_ws, size_t ws_size,
                              hipStream_t stream) {
  const float* seq   = (const float*)d_in[0];
  const int*   mask  = (const int*)d_in[1];
  const float* W_emb = (const float*)d_in[2];
  const float* b_emb = (const float*)d_in[3];
  const float* pos   = (const float*)d_in[4];
  const float* Wq = (const float*)d_in[5];  const float* bq = (const float*)d_in[6];
  const float* Wk = (const float*)d_in[7];  const float* bk = (const float*)d_in[8];
  const float* Wv = (const float*)d_in[9];  const float* bv = (const float*)d_in[10];
  const float* Wo = (const float*)d_in[11]; const float* bo = (const float*)d_in[12];
  const float* ln1g = (const float*)d_in[13]; const float* ln1b = (const float*)d_in[14];
  const float* ln2g = (const float*)d_in[15]; const float* ln2b = (const float*)d_in[16];
  const float* W1 = (const float*)d_in[17]; const float* b1 = (const float*)d_in[18];
  const float* W2 = (const float*)d_in[19]; const float* b2 = (const float*)d_in[20];
  float* outp = (float*)d_out;

  char* w = (char*)d_ws;
  float*  x_f32    = (float*)w;           w += (size_t)NTOK * E_ * 4;
  float*  proj_f32 = (float*)w;           w += (size_t)NTOK * E_ * 4;
  float*  bqkv     = (float*)w;           w += (size_t)L_ * 1536 * 4;
  unsigned short* x_b    = (unsigned short*)w; w += (size_t)NTOK * E_ * 2;
  unsigned short* q_b    = (unsigned short*)w; w += (size_t)NTOK * E_ * 2;
  unsigned short* k_b    = (unsigned short*)w; w += (size_t)NTOK * E_ * 2;
  unsigned short* vt_b   = (unsigned short*)w; w += (size_t)NTOK * E_ * 2;
  unsigned short* at_b   = (unsigned short*)w; w += (size_t)NTOK * E_ * 2;
  unsigned short* ffn_b  = (unsigned short*)w; w += (size_t)NTOK * FF_ * 2;
  unsigned short* Wqkv_b = (unsigned short*)w; w += (size_t)L_ * 1536 * E_ * 2;
  unsigned short* Wo_b   = (unsigned short*)w; w += (size_t)L_ * E_ * E_ * 2;
  unsigned short* W1_b   = (unsigned short*)w; w += (size_t)L_ * E_ * FF_ * 2;
  unsigned short* W2_b   = (unsigned short*)w; w += (size_t)L_ * FF_ * E_ * 2;

  const float qscale = 0.04419417382415922f;  // 1/sqrt(512)

  // weight transpose + convert: [L][K][N] f32 -> [L][N][K] bf16 (qscale folded into Wq)
  transpose_bf16<<<dim3(E_/32, E_/32, L_), 256, 0, stream>>>(Wq, Wqkv_b,            E_, E_, (size_t)1536*E_, qscale);
  transpose_bf16<<<dim3(E_/32, E_/32, L_), 256, 0, stream>>>(Wk, Wqkv_b + 512*E_,   E_, E_, (size_t)1536*E_, 1.f);
  transpose_bf16<<<dim3(E_/32, E_/32, L_), 256, 0, stream>>>(Wv, Wqkv_b + 1024*E_,  E_, E_, (size_t)1536*E_, 1.f);
  transpose_bf16<<<dim3(E_/32, E_/32, L_), 256, 0, stream>>>(Wo, Wo_b, E_, E_, (size_t)E_*E_, 1.f);
  transpose_bf16<<<dim3(FF_/32, E_/32, L_), 256, 0, stream>>>(W1, W1_b, E_, FF_, (size_t)E_*FF_, 1.f);
  transpose_bf16<<<dim3(E_/32, FF_/32, L_), 256, 0, stream>>>(W2, W2_b, FF_, E_, (size_t)FF_*E_, 1.f);
  build_bqkv<<<(L_ * 1536 + 255) / 256, 256, 0, stream>>>(bq, bk, bv, bqkv, qscale);

  embed_kernel<<<NTOK, 256, 0, stream>>>(seq, W_emb, b_emb, pos, x_f32, x_b);

  dim3 gqkv(1536 / 64, NTOK / 128);
  dim3 g512(E_ / 64, NTOK / 128);
  dim3 gff(FF_ / 128, NTOK / 128);
  for (int i = 0; i < L_; ++i) {
    gemm_tn<64, false, 1><<<gqkv, 256, 0, stream>>>(x_b, Wqkv_b + (size_t)i * 1536 * E_,
                                                    bqkv + i * 1536, nullptr, q_b, k_b, vt_b,
                                                    NTOK, 1536, E_);
    attn_mfma<<<B_ * H_ * (S_ / 64), 256, 0, stream>>>(q_b, k_b, vt_b, mask, at_b);
    gemm_tn<64, false, 0><<<g512, 256, 0, stream>>>(at_b, Wo_b + (size_t)i * E_ * E_, bo + i * E_,
                                                    proj_f32, nullptr, nullptr, nullptr,
                                                    NTOK, E_, E_);
    ln_kernel<<<NTOK / 4, 256, 0, stream>>>(proj_f32, x_f32, ln1g + i * E_, ln1b + i * E_,
                                            x_f32, x_b);
    gemm_tn<128, true, 0><<<gff, 256, 0, stream>>>(x_b, W1_b + (size_t)i * E_ * FF_, b1 + i * FF_,
                                                   nullptr, ffn_b, nullptr, nullptr,
                                                   NTOK, FF_, E_);
    gemm_tn<64, false, 0><<<g512, 256, 0, stream>>>(ffn_b, W2_b + (size_t)i * FF_ * E_, b2 + i * E_,
                                                    proj_f32, nullptr, nullptr, nullptr,
                                                    NTOK, E_, FF_);
    float* xdst = (i == L_ - 1) ? outp : x_f32;
    ln_kernel<<<NTOK / 4, 256, 0, stream>>>(proj_f32, x_f32, ln2g + i * E_, ln2b + i * E_,
                                            xdst, x_b);
  }
}

// Round 8
// 719.781 us; speedup vs baseline: 6.1946x; 1.4481x over previous
//
#include <hip/hip_runtime.h>
#include <hip/hip_bf16.h>

#define B_ 2
#define S_ 2048
#define F_ 64
#define E_ 512
#define H_ 8
#define L_ 4
#define FF_ 2048
#define NTOK (B_*S_)
#define DH 64

typedef __attribute__((ext_vector_type(8))) short bf16x8;
typedef __attribute__((ext_vector_type(4))) float f32x4;

__device__ __forceinline__ float b2f(unsigned short u) {
  union { unsigned int i; float f; } x; x.i = ((unsigned int)u) << 16; return x.f;
}
__device__ __forceinline__ unsigned short f2b(float f) {
  union { float f; unsigned int i; } x; x.f = f;
  unsigned int r = x.i + 0x7fffu + ((x.i >> 16) & 1u);
  return (unsigned short)(r >> 16);
}

// ---------------- tiled transpose + f32->bf16 (+scale): W[z][K][N] -> Wt[z][N][K] ----------------
__global__ __launch_bounds__(256)
void transpose_bf16(const float* __restrict__ W, unsigned short* __restrict__ Wt,
                    int K, int N, size_t zstride, float scale) {
  __shared__ unsigned short tile[32][33];
  const float* Wz = W + (size_t)blockIdx.z * K * N;
  unsigned short* Wtz = Wt + (size_t)blockIdx.z * zstride;
  const int n0 = blockIdx.x * 32, k0 = blockIdx.y * 32;
  const int tx = threadIdx.x & 31, ty = threadIdx.x >> 5;
#pragma unroll
  for (int i = 0; i < 4; ++i)
    tile[tx][ty + i * 8] = f2b(Wz[(size_t)(k0 + ty + i * 8) * N + n0 + tx] * scale);
  __syncthreads();
#pragma unroll
  for (int i = 0; i < 4; ++i)
    Wtz[(size_t)(n0 + ty + i * 8) * K + k0 + tx] = tile[ty + i * 8][tx];
}

// ---------------- concat qkv bias (qscale folded into q part) ----------------
__global__ __launch_bounds__(256)
void build_bqkv(const float* __restrict__ bq, const float* __restrict__ bk,
                const float* __restrict__ bv, float* __restrict__ out, float qs) {
  int i = blockIdx.x * 256 + threadIdx.x;
  if (i >= L_ * 1536) return;
  int l = i / 1536, c = i - l * 1536;
  float v;
  if (c < 512) v = bq[l * 512 + c] * qs;
  else if (c < 1024) v = bk[l * 512 + c - 512];
  else v = bv[l * 512 + c - 1024];
  out[i] = v;
}

// ---------------- mask -> per-64-key-tile u64 bitmask ----------------
__global__ __launch_bounds__(64)
void build_maskbits(const int* __restrict__ mask, unsigned long long* __restrict__ bm) {
  unsigned long long v = __ballot(mask[blockIdx.x * 64 + threadIdx.x] != 0);
  if (threadIdx.x == 0) bm[blockIdx.x] = v;
}

// ---------------- embedding: x = seq @ W_emb + b + pos ----------------
__global__ __launch_bounds__(256)
void embed_kernel(const float* __restrict__ seq, const float* __restrict__ W,
                  const float* __restrict__ be, const float* __restrict__ pe,
                  float* __restrict__ xf, unsigned short* __restrict__ xb) {
  const int n = blockIdx.x;
  const int s = n & (S_ - 1);
  __shared__ float srow[F_];
  if (threadIdx.x < F_) srow[threadIdx.x] = seq[(size_t)n * F_ + threadIdx.x];
  __syncthreads();
  for (int e = threadIdx.x; e < E_; e += 256) {
    float acc = be[e] + pe[(size_t)s * E_ + e];
#pragma unroll 8
    for (int f = 0; f < F_; ++f) acc = fmaf(srow[f], W[(size_t)f * E_ + e], acc);
    xf[(size_t)n * E_ + e] = acc;
    xb[(size_t)n * E_ + e] = f2b(acc);
  }
}

// ---------------- bf16 MFMA GEMM, A[M,K] @ Bt^T + bias (Bt is [N][K]) ----------------
// MODE 0: Cf (f32), Cb (bf16), Ct (bf16 transposed) — any may be null.
// MODE 1 (fused QKV, N=1536): col<512 -> Cb (q), col<1024 -> Cb2 (k), else Ct (v transposed).
template<int BN, bool RELU, int MODE>
__global__ __launch_bounds__(256)
void gemm_tn(const unsigned short* __restrict__ A, const unsigned short* __restrict__ Bt,
             const float* __restrict__ bias,
             float* __restrict__ Cf, unsigned short* __restrict__ Cb,
             unsigned short* __restrict__ Cb2, unsigned short* __restrict__ Ct,
             int M, int N, int K) {
  constexpr int BM = 128, BK = 32;
  constexpr int FN = BN / 32;   // fragment cols per wave (2-wide wave grid)
  constexpr int WN = BN / 2;    // wave col extent
  __shared__ unsigned short Alds[BM][BK + 8];
  __shared__ unsigned short Blds[BN][BK + 8];
  const int t = threadIdx.x;
  const int wid = t >> 6, lane = t & 63;
  const int wr = wid >> 1, wc = wid & 1;
  const int rowBase = blockIdx.y * BM;
  const int colBase = blockIdx.x * BN;

  f32x4 acc[4][FN];
#pragma unroll
  for (int i = 0; i < 4; ++i)
#pragma unroll
    for (int j = 0; j < FN; ++j) acc[i][j] = (f32x4){0.f, 0.f, 0.f, 0.f};

  const int lr = lane & 15;
  const int kb = (lane >> 4) * 8;

  for (int k0 = 0; k0 < K; k0 += BK) {
#pragma unroll
    for (int it = 0; it < (BM * BK / 8) / 256; ++it) {
      int idx = it * 256 + t;
      int r = idx >> 2;
      int c = (idx & 3) << 3;
      *(uint4*)&Alds[r][c] = *(const uint4*)&A[(size_t)(rowBase + r) * K + k0 + c];
    }
#pragma unroll
    for (int it = 0; it < (BN * BK / 8) / 256; ++it) {
      int idx = it * 256 + t;
      int r = idx >> 2;
      int c = (idx & 3) << 3;
      *(uint4*)&Blds[r][c] = *(const uint4*)&Bt[(size_t)(colBase + r) * K + k0 + c];
    }
    __syncthreads();

    bf16x8 af[4];
#pragma unroll
    for (int fm = 0; fm < 4; ++fm)
      af[fm] = *(const bf16x8*)&Alds[wr * 64 + fm * 16 + lr][kb];
#pragma unroll
    for (int fn = 0; fn < FN; ++fn) {
      bf16x8 bfr = *(const bf16x8*)&Blds[wc * WN + fn * 16 + lr][kb];
#pragma unroll
      for (int fm = 0; fm < 4; ++fm)
        acc[fm][fn] = __builtin_amdgcn_mfma_f32_16x16x32_bf16(af[fm], bfr, acc[fm][fn], 0, 0, 0);
    }
    __syncthreads();
  }

#pragma unroll
  for (int fm = 0; fm < 4; ++fm) {
#pragma unroll
    for (int fn = 0; fn < FN; ++fn) {
      int col = colBase + wc * WN + fn * 16 + lr;
      float bz = bias[col];
      int row0 = rowBase + wr * 64 + fm * 16 + (lane >> 4) * 4;
      float vv[4];
#pragma unroll
      for (int j = 0; j < 4; ++j) {
        float v = acc[fm][fn][j] + bz;
        if (RELU) v = fmaxf(v, 0.f);
        vv[j] = v;
      }
      if (MODE == 1) {
        int sel = col >> 9, lcol = col & 511;
        if (sel == 0) {
#pragma unroll
          for (int j = 0; j < 4; ++j) Cb[(size_t)(row0 + j) * E_ + lcol] = f2b(vv[j]);
        } else if (sel == 1) {
#pragma unroll
          for (int j = 0; j < 4; ++j) Cb2[(size_t)(row0 + j) * E_ + lcol] = f2b(vv[j]);
        } else {
          uint2 pk;
          pk.x = (unsigned)f2b(vv[0]) | ((unsigned)f2b(vv[1]) << 16);
          pk.y = (unsigned)f2b(vv[2]) | ((unsigned)f2b(vv[3]) << 16);
          *(uint2*)&Ct[(size_t)lcol * M + row0] = pk;
        }
      } else {
        if (Cf) {
#pragma unroll
          for (int j = 0; j < 4; ++j) Cf[(size_t)(row0 + j) * N + col] = vv[j];
        }
        if (Cb) {
#pragma unroll
          for (int j = 0; j < 4; ++j) Cb[(size_t)(row0 + j) * N + col] = f2b(vv[j]);
        }
        if (Ct) {
          uint2 pk;
          pk.x = (unsigned)f2b(vv[0]) | ((unsigned)f2b(vv[1]) << 16);
          pk.y = (unsigned)f2b(vv[2]) | ((unsigned)f2b(vv[3]) << 16);
          *(uint2*)&Ct[(size_t)col * M + row0] = pk;
        }
      }
    }
  }
}

// ---------------- MFMA flash attention, LDS-staged K/V (double-buffered) ----------------
// 4 waves/block share each 64-key K/V tile via LDS (kills the 45x per-wave L2 re-read).
// XOR-swizzled LDS layout (col ^= (row&7)<<3, ushort units) -> conflict-free b128 frags.
// T14 staging: issue global loads at top, ds_write after compute, one barrier per tile.
// Fixed-max softmax (scale-invariant, mask->P=0): l summed per-lane, reduced in epilogue.
__global__ __launch_bounds__(256, 2)
void attn_mfma(const unsigned short* __restrict__ qg, const unsigned short* __restrict__ kg,
               const unsigned short* __restrict__ vt, const unsigned long long* __restrict__ bm,
               unsigned short* __restrict__ outg) {
  __shared__ unsigned short Kl[2][64][64];
  __shared__ unsigned short Vl[2][64][64];
  __shared__ unsigned short plds[4][16][72];
  const int t = threadIdx.x;
  const int wid = t >> 6, lane = t & 63;
  const int g = lane >> 4, lr = lane & 15;
  // XCD-aware swizzle: blocks on one XCD share (b,h) -> K/V stays L2-resident
  const int bid = blockIdx.x;
  const int xcd = bid & 7, idx = bid >> 3;
  const int bh = xcd * 2 + (idx >> 5);   // 0..15
  const int qt = idx & 31;
  const int h = bh & 7, b = bh >> 3;
  const int bS = b * S_;
  const int qrow = bS + qt * 64 + wid * 16;
  const int hd = h * DH;

  // staging geometry: thread covers 2 rows per tile-half; row j*32+srow, col chunk scol
  const int srow = t >> 3;            // 0..31
  const int scol = (t & 7) * 8;       // ushort offset, 16B chunks
  const int ssw = scol ^ ((srow & 7) << 3);   // swizzled col (same for row and row+32)
  const unsigned short* ksrc = kg + (size_t)bS * E_ + hd;
  const unsigned short* vsrc = vt + (size_t)hd * NTOK + bS;
  const unsigned long long* bmb = bm + b * 32;

  bf16x8 aq0, aq1;
  {
    const unsigned short* qp = qg + (size_t)(qrow + lr) * E_ + hd + g * 8;
    aq0 = *(const bf16x8*)qp;
    aq1 = *(const bf16x8*)(qp + 32);
  }

  f32x4 O[4];
#pragma unroll
  for (int dt = 0; dt < 4; ++dt) O[dt] = (f32x4){0.f, 0.f, 0.f, 0.f};
  float lp[4] = {0.f, 0.f, 0.f, 0.f};

  // prologue: stage tile 0 into buffer 0
  {
    uint4 a = *(const uint4*)&ksrc[(size_t)srow * E_ + scol];
    uint4 c = *(const uint4*)&ksrc[(size_t)(32 + srow) * E_ + scol];
    uint4 d = *(const uint4*)&vsrc[(size_t)srow * NTOK + scol];
    uint4 e = *(const uint4*)&vsrc[(size_t)(srow + 32) * NTOK + scol];
    *(uint4*)&Kl[0][srow][ssw] = a;
    *(uint4*)&Kl[0][srow + 32][ssw] = c;
    *(uint4*)&Vl[0][srow][ssw] = d;
    *(uint4*)&Vl[0][srow + 32][ssw] = e;
  }
  __syncthreads();

  int cur = 0;
#pragma unroll 2
  for (int kt = 0; kt < 32; ++kt) {
    // ---- issue next-tile loads (consumed after compute -> latency hidden) ----
    uint4 nk0, nk1, nv0, nv1;
    const int nkb = (kt + 1) * 64;
    if (kt < 31) {
      nk0 = *(const uint4*)&ksrc[(size_t)(nkb + srow) * E_ + scol];
      nk1 = *(const uint4*)&ksrc[(size_t)(nkb + 32 + srow) * E_ + scol];
      nv0 = *(const uint4*)&vsrc[(size_t)srow * NTOK + nkb + scol];
      nv1 = *(const uint4*)&vsrc[(size_t)(srow + 32) * NTOK + nkb + scol];
    }
    const unsigned long long bmv = bmb[kt];
    // ---- S = Q K^T from LDS K frags ----
    f32x4 s_[4];
#pragma unroll
    for (int t16 = 0; t16 < 4; ++t16) {
      const int row = t16 * 16 + lr;
      const int sw = (row & 7) << 3;
      bf16x8 b0 = *(const bf16x8*)&Kl[cur][row][(g * 8) ^ sw];
      bf16x8 b1 = *(const bf16x8*)&Kl[cur][row][(32 + g * 8) ^ sw];
      f32x4 z = (f32x4){0.f, 0.f, 0.f, 0.f};
      z = __builtin_amdgcn_mfma_f32_16x16x32_bf16(aq0, b0, z, 0, 0, 0);
      z = __builtin_amdgcn_mfma_f32_16x16x32_bf16(aq1, b1, z, 0, 0, 0);
      s_[t16] = z;
    }
    // ---- P = exp(S) (fixed-max), mask via bitmask ----
    float p_[4][4];
#pragma unroll
    for (int t16 = 0; t16 < 4; ++t16)
#pragma unroll
      for (int j = 0; j < 4; ++j) p_[t16][j] = __expf(fminf(s_[t16][j], 45.f));
    if (bmv != ~0ull) {
#pragma unroll
      for (int t16 = 0; t16 < 4; ++t16)
        if (!((bmv >> (t16 * 16 + lr)) & 1)) {
#pragma unroll
          for (int j = 0; j < 4; ++j) p_[t16][j] = 0.f;
        }
    }
#pragma unroll
    for (int j = 0; j < 4; ++j)
      lp[j] += (p_[0][j] + p_[1][j]) + (p_[2][j] + p_[3][j]);
    // ---- P (C layout) -> LDS -> A-fragment layout ----
#pragma unroll
    for (int t16 = 0; t16 < 4; ++t16)
#pragma unroll
      for (int j = 0; j < 4; ++j)
        plds[wid][g * 4 + j][t16 * 16 + lr] = f2b(p_[t16][j]);
    asm volatile("s_waitcnt lgkmcnt(0)" ::: "memory");
    __builtin_amdgcn_sched_barrier(0);
    bf16x8 pa0 = *(const bf16x8*)&plds[wid][lr][g * 8];
    bf16x8 pa1 = *(const bf16x8*)&plds[wid][lr][32 + g * 8];
    // ---- O += P V from LDS V frags ----
#pragma unroll
    for (int dt = 0; dt < 4; ++dt) {
      const int row = dt * 16 + lr;
      const int sw = (row & 7) << 3;
      bf16x8 v0 = *(const bf16x8*)&Vl[cur][row][(g * 8) ^ sw];
      bf16x8 v1 = *(const bf16x8*)&Vl[cur][row][(32 + g * 8) ^ sw];
      O[dt] = __builtin_amdgcn_mfma_f32_16x16x32_bf16(pa0, v0, O[dt], 0, 0, 0);
      O[dt] = __builtin_amdgcn_mfma_f32_16x16x32_bf16(pa1, v1, O[dt], 0, 0, 0);
    }
    // ---- write staged tile kt+1 into the other buffer, then sync ----
    if (kt < 31) {
      *(uint4*)&Kl[cur ^ 1][srow][ssw] = nk0;
      *(uint4*)&Kl[cur ^ 1][srow + 32][ssw] = nk1;
      *(uint4*)&Vl[cur ^ 1][srow][ssw] = nv0;
      *(uint4*)&Vl[cur ^ 1][srow + 32][ssw] = nv1;
    }
    __syncthreads();
    cur ^= 1;
  }

  // epilogue: reduce l across the 16-lane column group, then normalize
#pragma unroll
  for (int j = 0; j < 4; ++j) {
    float v = lp[j];
    v += __shfl_xor(v, 1);
    v += __shfl_xor(v, 2);
    v += __shfl_xor(v, 4);
    v += __shfl_xor(v, 8);
    lp[j] = 1.f / v;
  }
#pragma unroll
  for (int dt = 0; dt < 4; ++dt)
#pragma unroll
    for (int j = 0; j < 4; ++j)
      outg[(size_t)(qrow + g * 4 + j) * E_ + hd + dt * 16 + lr] = f2b(O[dt][j] * lp[j]);
}

// ---------------- fused residual + layernorm (+ bf16 recast) ----------------
__global__ __launch_bounds__(256)
void ln_kernel(const float* __restrict__ y, const float* __restrict__ xin,
               const float* __restrict__ g, const float* __restrict__ bb,
               float* __restrict__ xf, unsigned short* __restrict__ xb) {
  const int t = threadIdx.x, wid = t >> 6, lane = t & 63;
  const int row = blockIdx.x * 4 + wid;
  const float* yr = y + (size_t)row * E_;
  const float* xr = xin + (size_t)row * E_;
  float vals[8];
  float s = 0.f;
#pragma unroll
  for (int j = 0; j < 8; ++j) {
    float val = yr[lane * 8 + j] + xr[lane * 8 + j];
    vals[j] = val; s += val;
  }
#pragma unroll
  for (int off = 32; off > 0; off >>= 1) s += __shfl_xor(s, off);
  float mean = s * (1.f / 512.f);
  float vv = 0.f;
#pragma unroll
  for (int j = 0; j < 8; ++j) { float d = vals[j] - mean; vv += d * d; }
#pragma unroll
  for (int off = 32; off > 0; off >>= 1) vv += __shfl_xor(vv, off);
  float inv = rsqrtf(vv * (1.f / 512.f) + 1e-5f);
#pragma unroll
  for (int j = 0; j < 8; ++j) {
    int col = lane * 8 + j;
    float r = (vals[j] - mean) * inv * g[col] + bb[col];
    xf[(size_t)row * E_ + col] = r;
    xb[(size_t)row * E_ + col] = f2b(r);
  }
}

extern "C" void kernel_launch(void* const* d_in, const int* in_sizes, int n_in,
                              void* d_out, int out_size, void* d_ws, size_t ws_size,
                              hipStream_t stream) {
  const float* seq   = (const float*)d_in[0];
  const int*   mask  = (const int*)d_in[1];
  const float* W_emb = (const float*)d_in[2];
  const float* b_emb = (const float*)d_in[3];
  const float* pos   = (const float*)d_in[4];
  const float* Wq = (const float*)d_in[5];  const float* bq = (const float*)d_in[6];
  const float* Wk = (const float*)d_in[7];  const float* bk = (const float*)d_in[8];
  const float* Wv = (const float*)d_in[9];  const float* bv = (const float*)d_in[10];
  const float* Wo = (const float*)d_in[11]; const float* bo = (const float*)d_in[12];
  const float* ln1g = (const float*)d_in[13]; const float* ln1b = (const float*)d_in[14];
  const float* ln2g = (const float*)d_in[15]; const float* ln2b = (const float*)d_in[16];
  const float* W1 = (const float*)d_in[17]; const float* b1 = (const float*)d_in[18];
  const float* W2 = (const float*)d_in[19]; const float* b2 = (const float*)d_in[20];
  float* outp = (float*)d_out;

  char* w = (char*)d_ws;
  float*  x_f32    = (float*)w;           w += (size_t)NTOK * E_ * 4;
  float*  proj_f32 = (float*)w;           w += (size_t)NTOK * E_ * 4;
  float*  bqkv     = (float*)w;           w += (size_t)L_ * 1536 * 4;
  unsigned long long* bmw = (unsigned long long*)w; w += (size_t)B_ * 32 * 8;
  unsigned short* x_b    = (unsigned short*)w; w += (size_t)NTOK * E_ * 2;
  unsigned short* q_b    = (unsigned short*)w; w += (size_t)NTOK * E_ * 2;
  unsigned short* k_b    = (unsigned short*)w; w += (size_t)NTOK * E_ * 2;
  unsigned short* vt_b   = (unsigned short*)w; w += (size_t)NTOK * E_ * 2;
  unsigned short* at_b   = (unsigned short*)w; w += (size_t)NTOK * E_ * 2;
  unsigned short* ffn_b  = (unsigned short*)w; w += (size_t)NTOK * FF_ * 2;
  unsigned short* Wqkv_b = (unsigned short*)w; w += (size_t)L_ * 1536 * E_ * 2;
  unsigned short* Wo_b   = (unsigned short*)w; w += (size_t)L_ * E_ * E_ * 2;
  unsigned short* W1_b   = (unsigned short*)w; w += (size_t)L_ * E_ * FF_ * 2;
  unsigned short* W2_b   = (unsigned short*)w; w += (size_t)L_ * FF_ * E_ * 2;

  const float qscale = 0.04419417382415922f;  // 1/sqrt(512)

  // weight transpose + convert: [L][K][N] f32 -> [L][N][K] bf16 (qscale folded into Wq)
  transpose_bf16<<<dim3(E_/32, E_/32, L_), 256, 0, stream>>>(Wq, Wqkv_b,            E_, E_, (size_t)1536*E_, qscale);
  transpose_bf16<<<dim3(E_/32, E_/32, L_), 256, 0, stream>>>(Wk, Wqkv_b + 512*E_,   E_, E_, (size_t)1536*E_, 1.f);
  transpose_bf16<<<dim3(E_/32, E_/32, L_), 256, 0, stream>>>(Wv, Wqkv_b + 1024*E_,  E_, E_, (size_t)1536*E_, 1.f);
  transpose_bf16<<<dim3(E_/32, E_/32, L_), 256, 0, stream>>>(Wo, Wo_b, E_, E_, (size_t)E_*E_, 1.f);
  transpose_bf16<<<dim3(FF_/32, E_/32, L_), 256, 0, stream>>>(W1, W1_b, E_, FF_, (size_t)E_*FF_, 1.f);
  transpose_bf16<<<dim3(E_/32, FF_/32, L_), 256, 0, stream>>>(W2, W2_b, FF_, E_, (size_t)FF_*E_, 1.f);
  build_bqkv<<<(L_ * 1536 + 255) / 256, 256, 0, stream>>>(bq, bk, bv, bqkv, qscale);
  build_maskbits<<<B_ * 32, 64, 0, stream>>>(mask, bmw);

  embed_kernel<<<NTOK, 256, 0, stream>>>(seq, W_emb, b_emb, pos, x_f32, x_b);

  dim3 gqkv(1536 / 64, NTOK / 128);
  dim3 g512(E_ / 64, NTOK / 128);
  dim3 gff(FF_ / 128, NTOK / 128);
  for (int i = 0; i < L_; ++i) {
    gemm_tn<64, false, 1><<<gqkv, 256, 0, stream>>>(x_b, Wqkv_b + (size_t)i * 1536 * E_,
                                                    bqkv + i * 1536, nullptr, q_b, k_b, vt_b,
                                                    NTOK, 1536, E_);
    attn_mfma<<<B_ * H_ * (S_ / 64), 256, 0, stream>>>(q_b, k_b, vt_b, bmw, at_b);
    gemm_tn<64, false, 0><<<g512, 256, 0, stream>>>(at_b, Wo_b + (size_t)i * E_ * E_, bo + i * E_,
                                                    proj_f32, nullptr, nullptr, nullptr,
                                                    NTOK, E_, E_);
    ln_kernel<<<NTOK / 4, 256, 0, stream>>>(proj_f32, x_f32, ln1g + i * E_, ln1b + i * E_,
                                            x_f32, x_b);
    gemm_tn<128, true, 0><<<gff, 256, 0, stream>>>(x_b, W1_b + (size_t)i * E_ * FF_, b1 + i * FF_,
                                                   nullptr, ffn_b, nullptr, nullptr,
                                                   NTOK, FF_, E_);
    gemm_tn<64, false, 0><<<g512, 256, 0, stream>>>(ffn_b, W2_b + (size_t)i * FF_ * E_, b2 + i * E_,
                                                    proj_f32, nullptr, nullptr, nullptr,
                                                    NTOK, E_, FF_);
    float* xdst = (i == L_ - 1) ? outp : x_f32;
    ln_kernel<<<NTOK / 4, 256, 0, stream>>>(proj_f32, x_f32, ln2g + i * E_, ln2b + i * E_,
                                            xdst, x_b);
  }
}

// Round 10
// 692.673 us; speedup vs baseline: 6.4370x; 1.0391x over previous
//
#include <hip/hip_runtime.h>
#include <hip/hip_bf16.h>

#define B_ 2
#define S_ 2048
#define F_ 64
#define E_ 512
#define H_ 8
#define L_ 4
#define FF_ 2048
#define NTOK (B_*S_)
#define DH 64

typedef __attribute__((ext_vector_type(8))) short bf16x8;
typedef __attribute__((ext_vector_type(4))) float f32x4;

typedef const __attribute__((address_space(1))) void* gptr_t;
typedef __attribute__((address_space(3))) void* lptr_t;

__device__ __forceinline__ float b2f(unsigned short u) {
  union { unsigned int i; float f; } x; x.i = ((unsigned int)u) << 16; return x.f;
}
__device__ __forceinline__ unsigned short f2b(float f) {
  union { float f; unsigned int i; } x; x.f = f;
  unsigned int r = x.i + 0x7fffu + ((x.i >> 16) & 1u);
  return (unsigned short)(r >> 16);
}

// ---------------- tiled transpose + f32->bf16 (+scale): W[z][K][N] -> Wt[z][N][K] ----------------
__global__ __launch_bounds__(256)
void transpose_bf16(const float* __restrict__ W, unsigned short* __restrict__ Wt,
                    int K, int N, size_t zstride, float scale) {
  __shared__ unsigned short tile[32][33];
  const float* Wz = W + (size_t)blockIdx.z * K * N;
  unsigned short* Wtz = Wt + (size_t)blockIdx.z * zstride;
  const int n0 = blockIdx.x * 32, k0 = blockIdx.y * 32;
  const int tx = threadIdx.x & 31, ty = threadIdx.x >> 5;
#pragma unroll
  for (int i = 0; i < 4; ++i)
    tile[tx][ty + i * 8] = f2b(Wz[(size_t)(k0 + ty + i * 8) * N + n0 + tx] * scale);
  __syncthreads();
#pragma unroll
  for (int i = 0; i < 4; ++i)
    Wtz[(size_t)(n0 + ty + i * 8) * K + k0 + tx] = tile[ty + i * 8][tx];
}

// ---------------- concat qkv bias (qscale folded into q part) ----------------
__global__ __launch_bounds__(256)
void build_bqkv(const float* __restrict__ bq, const float* __restrict__ bk,
                const float* __restrict__ bv, float* __restrict__ out, float qs) {
  int i = blockIdx.x * 256 + threadIdx.x;
  if (i >= L_ * 1536) return;
  int l = i / 1536, c = i - l * 1536;
  float v;
  if (c < 512) v = bq[l * 512 + c] * qs;
  else if (c < 1024) v = bk[l * 512 + c - 512];
  else v = bv[l * 512 + c - 1024];
  out[i] = v;
}

// ---------------- mask -> per-64-key-tile u64 bitmask ----------------
__global__ __launch_bounds__(64)
void build_maskbits(const int* __restrict__ mask, unsigned long long* __restrict__ bm) {
  unsigned long long v = __ballot(mask[blockIdx.x * 64 + threadIdx.x] != 0);
  if (threadIdx.x == 0) bm[blockIdx.x] = v;
}

// ---------------- embedding: x = seq @ W_emb + b + pos ----------------
__global__ __launch_bounds__(256)
void embed_kernel(const float* __restrict__ seq, const float* __restrict__ W,
                  const float* __restrict__ be, const float* __restrict__ pe,
                  float* __restrict__ xf, unsigned short* __restrict__ xb) {
  const int n = blockIdx.x;
  const int s = n & (S_ - 1);
  __shared__ float srow[F_];
  if (threadIdx.x < F_) srow[threadIdx.x] = seq[(size_t)n * F_ + threadIdx.x];
  __syncthreads();
  for (int e = threadIdx.x; e < E_; e += 256) {
    float acc = be[e] + pe[(size_t)s * E_ + e];
#pragma unroll 8
    for (int f = 0; f < F_; ++f) acc = fmaf(srow[f], W[(size_t)f * E_ + e], acc);
    xf[(size_t)n * E_ + e] = acc;
    xb[(size_t)n * E_ + e] = f2b(acc);
  }
}

// ---------------- bf16 MFMA GEMM, A[M,K] @ Bt^T + bias (Bt is [N][K]) ----------------
// Staging via global_load_lds width=16 into LINEAR LDS (wave-uniform base + lane*16).
// Frag b128 reads cover contiguous 1024B blocks -> conflict-free, no padding needed.
// MODE 0: Cf (f32), Cb (bf16), Ct (bf16 transposed) — any may be null.
// MODE 1 (fused QKV, N=1536): col<512 -> Cb (q), col<1024 -> Cb2 (k), else Ct (v transposed).
template<int BN, bool RELU, int MODE>
__global__ __launch_bounds__(256)
void gemm_tn(const unsigned short* __restrict__ A, const unsigned short* __restrict__ Bt,
             const float* __restrict__ bias,
             float* __restrict__ Cf, unsigned short* __restrict__ Cb,
             unsigned short* __restrict__ Cb2, unsigned short* __restrict__ Ct,
             int M, int N, int K) {
  constexpr int BM = 128, BK = 32;
  constexpr int FN = BN / 32;   // fragment cols per wave (2-wide wave grid)
  constexpr int WN = BN / 2;    // wave col extent
  __shared__ unsigned short Alds[BM * BK];
  __shared__ unsigned short Blds[BN * BK];
  const int t = threadIdx.x;
  const int wid = t >> 6, lane = t & 63;
  const int wr = wid >> 1, wc = wid & 1;
  const int rowBase = blockIdx.y * BM;
  const int colBase = blockIdx.x * BN;

  f32x4 acc[4][FN];
#pragma unroll
  for (int i = 0; i < 4; ++i)
#pragma unroll
    for (int j = 0; j < FN; ++j) acc[i][j] = (f32x4){0.f, 0.f, 0.f, 0.f};

  const int lr = lane & 15;
  const int g8 = (lane >> 4) * 8;

  // staging source (per lane): 16-row chunks, lane covers row sr, 16B chunk sc
  const int sr = lane >> 2;          // 0..15
  const int sc = (lane & 3) * 8;     // bf16 units
  const unsigned short* Ab0 = A + (size_t)(rowBase + wid * 32 + sr) * K + sc;
  const unsigned short* Ab1 = Ab0 + (size_t)16 * K;
  const unsigned short* Bb0;
  const unsigned short* Bb1;
  if (FN == 2) {
    Bb0 = Bt + (size_t)(colBase + wid * 16 + sr) * K + sc;
    Bb1 = nullptr;
  } else {
    Bb0 = Bt + (size_t)(colBase + wid * 32 + sr) * K + sc;
    Bb1 = Bb0 + (size_t)16 * K;
  }

  for (int k0 = 0; k0 < K; k0 += BK) {
    // ---- stage: direct global->LDS, 1024B per instr ----
    __builtin_amdgcn_global_load_lds((gptr_t)(Ab0 + k0), (lptr_t)&Alds[wid * 1024], 16, 0, 0);
    __builtin_amdgcn_global_load_lds((gptr_t)(Ab1 + k0), (lptr_t)&Alds[wid * 1024 + 512], 16, 0, 0);
    if (FN == 2) {
      __builtin_amdgcn_global_load_lds((gptr_t)(Bb0 + k0), (lptr_t)&Blds[wid * 512], 16, 0, 0);
    } else {
      __builtin_amdgcn_global_load_lds((gptr_t)(Bb0 + k0), (lptr_t)&Blds[wid * 1024], 16, 0, 0);
      __builtin_amdgcn_global_load_lds((gptr_t)(Bb1 + k0), (lptr_t)&Blds[wid * 1024 + 512], 16, 0, 0);
    }
    __syncthreads();

    bf16x8 af[4];
#pragma unroll
    for (int fm = 0; fm < 4; ++fm)
      af[fm] = *(const bf16x8*)&Alds[(wr * 64 + fm * 16 + lr) * 32 + g8];
#pragma unroll
    for (int fn = 0; fn < FN; ++fn) {
      bf16x8 bfr = *(const bf16x8*)&Blds[(wc * WN + fn * 16 + lr) * 32 + g8];
#pragma unroll
      for (int fm = 0; fm < 4; ++fm)
        acc[fm][fn] = __builtin_amdgcn_mfma_f32_16x16x32_bf16(af[fm], bfr, acc[fm][fn], 0, 0, 0);
    }
    __syncthreads();
  }

#pragma unroll
  for (int fm = 0; fm < 4; ++fm) {
#pragma unroll
    for (int fn = 0; fn < FN; ++fn) {
      int col = colBase + wc * WN + fn * 16 + lr;
      float bz = bias[col];
      int row0 = rowBase + wr * 64 + fm * 16 + (lane >> 4) * 4;
      float vv[4];
#pragma unroll
      for (int j = 0; j < 4; ++j) {
        float v = acc[fm][fn][j] + bz;
        if (RELU) v = fmaxf(v, 0.f);
        vv[j] = v;
      }
      if (MODE == 1) {
        int sel = col >> 9, lcol = col & 511;
        if (sel == 0) {
#pragma unroll
          for (int j = 0; j < 4; ++j) Cb[(size_t)(row0 + j) * E_ + lcol] = f2b(vv[j]);
        } else if (sel == 1) {
#pragma unroll
          for (int j = 0; j < 4; ++j) Cb2[(size_t)(row0 + j) * E_ + lcol] = f2b(vv[j]);
        } else {
          uint2 pk;
          pk.x = (unsigned)f2b(vv[0]) | ((unsigned)f2b(vv[1]) << 16);
          pk.y = (unsigned)f2b(vv[2]) | ((unsigned)f2b(vv[3]) << 16);
          *(uint2*)&Ct[(size_t)lcol * M + row0] = pk;
        }
      } else {
        if (Cf) {
#pragma unroll
          for (int j = 0; j < 4; ++j) Cf[(size_t)(row0 + j) * N + col] = vv[j];
        }
        if (Cb) {
#pragma unroll
          for (int j = 0; j < 4; ++j) Cb[(size_t)(row0 + j) * N + col] = f2b(vv[j]);
        }
        if (Ct) {
          uint2 pk;
          pk.x = (unsigned)f2b(vv[0]) | ((unsigned)f2b(vv[1]) << 16);
          pk.y = (unsigned)f2b(vv[2]) | ((unsigned)f2b(vv[3]) << 16);
          *(uint2*)&Ct[(size_t)col * M + row0] = pk;
        }
      }
    }
  }
}

// ---------------- MFMA flash attention, LDS-staged K/V (double-buffered) ----------------
__global__ __launch_bounds__(256, 2)
void attn_mfma(const unsigned short* __restrict__ qg, const unsigned short* __restrict__ kg,
               const unsigned short* __restrict__ vt, const unsigned long long* __restrict__ bm,
               unsigned short* __restrict__ outg) {
  __shared__ unsigned short Kl[2][64][64];
  __shared__ unsigned short Vl[2][64][64];
  __shared__ unsigned short plds[4][16][72];
  const int t = threadIdx.x;
  const int wid = t >> 6, lane = t & 63;
  const int g = lane >> 4, lr = lane & 15;
  // XCD-aware swizzle: blocks on one XCD share (b,h) -> K/V stays L2-resident
  const int bid = blockIdx.x;
  const int xcd = bid & 7, idx = bid >> 3;
  const int bh = xcd * 2 + (idx >> 5);   // 0..15
  const int qt = idx & 31;
  const int h = bh & 7, b = bh >> 3;
  const int bS = b * S_;
  const int qrow = bS + qt * 64 + wid * 16;
  const int hd = h * DH;

  const int srow = t >> 3;            // 0..31
  const int scol = (t & 7) * 8;       // ushort offset, 16B chunks
  const int ssw = scol ^ ((srow & 7) << 3);   // swizzled col
  const unsigned short* ksrc = kg + (size_t)bS * E_ + hd;
  const unsigned short* vsrc = vt + (size_t)hd * NTOK + bS;
  const unsigned long long* bmb = bm + b * 32;

  bf16x8 aq0, aq1;
  {
    const unsigned short* qp = qg + (size_t)(qrow + lr) * E_ + hd + g * 8;
    aq0 = *(const bf16x8*)qp;
    aq1 = *(const bf16x8*)(qp + 32);
  }

  f32x4 O[4];
#pragma unroll
  for (int dt = 0; dt < 4; ++dt) O[dt] = (f32x4){0.f, 0.f, 0.f, 0.f};
  float lp[4] = {0.f, 0.f, 0.f, 0.f};

  // prologue: stage tile 0 into buffer 0
  {
    uint4 a = *(const uint4*)&ksrc[(size_t)srow * E_ + scol];
    uint4 c = *(const uint4*)&ksrc[(size_t)(32 + srow) * E_ + scol];
    uint4 d = *(const uint4*)&vsrc[(size_t)srow * NTOK + scol];
    uint4 e = *(const uint4*)&vsrc[(size_t)(srow + 32) * NTOK + scol];
    *(uint4*)&Kl[0][srow][ssw] = a;
    *(uint4*)&Kl[0][srow + 32][ssw] = c;
    *(uint4*)&Vl[0][srow][ssw] = d;
    *(uint4*)&Vl[0][srow + 32][ssw] = e;
  }
  __syncthreads();

  int cur = 0;
#pragma unroll 2
  for (int kt = 0; kt < 32; ++kt) {
    uint4 nk0, nk1, nv0, nv1;
    const int nkb = (kt + 1) * 64;
    if (kt < 31) {
      nk0 = *(const uint4*)&ksrc[(size_t)(nkb + srow) * E_ + scol];
      nk1 = *(const uint4*)&ksrc[(size_t)(nkb + 32 + srow) * E_ + scol];
      nv0 = *(const uint4*)&vsrc[(size_t)srow * NTOK + nkb + scol];
      nv1 = *(const uint4*)&vsrc[(size_t)(srow + 32) * NTOK + nkb + scol];
    }
    const unsigned long long bmv = bmb[kt];
    f32x4 s_[4];
#pragma unroll
    for (int t16 = 0; t16 < 4; ++t16) {
      const int row = t16 * 16 + lr;
      const int sw = (row & 7) << 3;
      bf16x8 b0 = *(const bf16x8*)&Kl[cur][row][(g * 8) ^ sw];
      bf16x8 b1 = *(const bf16x8*)&Kl[cur][row][(32 + g * 8) ^ sw];
      f32x4 z = (f32x4){0.f, 0.f, 0.f, 0.f};
      z = __builtin_amdgcn_mfma_f32_16x16x32_bf16(aq0, b0, z, 0, 0, 0);
      z = __builtin_amdgcn_mfma_f32_16x16x32_bf16(aq1, b1, z, 0, 0, 0);
      s_[t16] = z;
    }
    float p_[4][4];
#pragma unroll
    for (int t16 = 0; t16 < 4; ++t16)
#pragma unroll
      for (int j = 0; j < 4; ++j) p_[t16][j] = __expf(fminf(s_[t16][j], 45.f));
    if (bmv != ~0ull) {
#pragma unroll
      for (int t16 = 0; t16 < 4; ++t16)
        if (!((bmv >> (t16 * 16 + lr)) & 1)) {
#pragma unroll
          for (int j = 0; j < 4; ++j) p_[t16][j] = 0.f;
        }
    }
#pragma unroll
    for (int j = 0; j < 4; ++j)
      lp[j] += (p_[0][j] + p_[1][j]) + (p_[2][j] + p_[3][j]);
#pragma unroll
    for (int t16 = 0; t16 < 4; ++t16)
#pragma unroll
      for (int j = 0; j < 4; ++j)
        plds[wid][g * 4 + j][t16 * 16 + lr] = f2b(p_[t16][j]);
    asm volatile("s_waitcnt lgkmcnt(0)" ::: "memory");
    __builtin_amdgcn_sched_barrier(0);
    bf16x8 pa0 = *(const bf16x8*)&plds[wid][lr][g * 8];
    bf16x8 pa1 = *(const bf16x8*)&plds[wid][lr][32 + g * 8];
#pragma unroll
    for (int dt = 0; dt < 4; ++dt) {
      const int row = dt * 16 + lr;
      const int sw = (row & 7) << 3;
      bf16x8 v0 = *(const bf16x8*)&Vl[cur][row][(g * 8) ^ sw];
      bf16x8 v1 = *(const bf16x8*)&Vl[cur][row][(32 + g * 8) ^ sw];
      O[dt] = __builtin_amdgcn_mfma_f32_16x16x32_bf16(pa0, v0, O[dt], 0, 0, 0);
      O[dt] = __builtin_amdgcn_mfma_f32_16x16x32_bf16(pa1, v1, O[dt], 0, 0, 0);
    }
    if (kt < 31) {
      *(uint4*)&Kl[cur ^ 1][srow][ssw] = nk0;
      *(uint4*)&Kl[cur ^ 1][srow + 32][ssw] = nk1;
      *(uint4*)&Vl[cur ^ 1][srow][ssw] = nv0;
      *(uint4*)&Vl[cur ^ 1][srow + 32][ssw] = nv1;
    }
    __syncthreads();
    cur ^= 1;
  }

#pragma unroll
  for (int j = 0; j < 4; ++j) {
    float v = lp[j];
    v += __shfl_xor(v, 1);
    v += __shfl_xor(v, 2);
    v += __shfl_xor(v, 4);
    v += __shfl_xor(v, 8);
    lp[j] = 1.f / v;
  }
#pragma unroll
  for (int dt = 0; dt < 4; ++dt)
#pragma unroll
    for (int j = 0; j < 4; ++j)
      outg[(size_t)(qrow + g * 4 + j) * E_ + hd + dt * 16 + lr] = f2b(O[dt][j] * lp[j]);
}

// ---------------- fused residual + layernorm (+ bf16 recast) ----------------
__global__ __launch_bounds__(256)
void ln_kernel(const float* __restrict__ y, const float* __restrict__ xin,
               const float* __restrict__ g, const float* __restrict__ bb,
               float* __restrict__ xf, unsigned short* __restrict__ xb) {
  const int t = threadIdx.x, wid = t >> 6, lane = t & 63;
  const int row = blockIdx.x * 4 + wid;
  const float* yr = y + (size_t)row * E_;
  const float* xr = xin + (size_t)row * E_;
  float vals[8];
  float s = 0.f;
#pragma unroll
  for (int j = 0; j < 8; ++j) {
    float val = yr[lane * 8 + j] + xr[lane * 8 + j];
    vals[j] = val; s += val;
  }
#pragma unroll
  for (int off = 32; off > 0; off >>= 1) s += __shfl_xor(s, off);
  float mean = s * (1.f / 512.f);
  float vv = 0.f;
#pragma unroll
  for (int j = 0; j < 8; ++j) { float d = vals[j] - mean; vv += d * d; }
#pragma unroll
  for (int off = 32; off > 0; off >>= 1) vv += __shfl_xor(vv, off);
  float inv = rsqrtf(vv * (1.f / 512.f) + 1e-5f);
#pragma unroll
  for (int j = 0; j < 8; ++j) {
    int col = lane * 8 + j;
    float r = (vals[j] - mean) * inv * g[col] + bb[col];
    xf[(size_t)row * E_ + col] = r;
    xb[(size_t)row * E_ + col] = f2b(r);
  }
}

extern "C" void kernel_launch(void* const* d_in, const int* in_sizes, int n_in,
                              void* d_out, int out_size, void* d_ws, size_t ws_size,
                              hipStream_t stream) {
  const float* seq   = (const float*)d_in[0];
  const int*   mask  = (const int*)d_in[1];
  const float* W_emb = (const float*)d_in[2];
  const float* b_emb = (const float*)d_in[3];
  const float* pos   = (const float*)d_in[4];
  const float* Wq = (const float*)d_in[5];  const float* bq = (const float*)d_in[6];
  const float* Wk = (const float*)d_in[7];  const float* bk = (const float*)d_in[8];
  const float* Wv = (const float*)d_in[9];  const float* bv = (const float*)d_in[10];
  const float* Wo = (const float*)d_in[11]; const float* bo = (const float*)d_in[12];
  const float* ln1g = (const float*)d_in[13]; const float* ln1b = (const float*)d_in[14];
  const float* ln2g = (const float*)d_in[15]; const float* ln2b = (const float*)d_in[16];
  const float* W1 = (const float*)d_in[17]; const float* b1 = (const float*)d_in[18];
  const float* W2 = (const float*)d_in[19]; const float* b2 = (const float*)d_in[20];
  float* outp = (float*)d_out;

  char* w = (char*)d_ws;
  float*  x_f32    = (float*)w;           w += (size_t)NTOK * E_ * 4;
  float*  proj_f32 = (float*)w;           w += (size_t)NTOK * E_ * 4;
  float*  bqkv     = (float*)w;           w += (size_t)L_ * 1536 * 4;
  unsigned long long* bmw = (unsigned long long*)w; w += (size_t)B_ * 32 * 8;
  unsigned short* x_b    = (unsigned short*)w; w += (size_t)NTOK * E_ * 2;
  unsigned short* q_b    = (unsigned short*)w; w += (size_t)NTOK * E_ * 2;
  unsigned short* k_b    = (unsigned short*)w; w += (size_t)NTOK * E_ * 2;
  unsigned short* vt_b   = (unsigned short*)w; w += (size_t)NTOK * E_ * 2;
  unsigned short* at_b   = (unsigned short*)w; w += (size_t)NTOK * E_ * 2;
  unsigned short* ffn_b  = (unsigned short*)w; w += (size_t)NTOK * FF_ * 2;
  unsigned short* Wqkv_b = (unsigned short*)w; w += (size_t)L_ * 1536 * E_ * 2;
  unsigned short* Wo_b   = (unsigned short*)w; w += (size_t)L_ * E_ * E_ * 2;
  unsigned short* W1_b   = (unsigned short*)w; w += (size_t)L_ * E_ * FF_ * 2;
  unsigned short* W2_b   = (unsigned short*)w; w += (size_t)L_ * FF_ * E_ * 2;

  const float qscale = 0.04419417382415922f;  // 1/sqrt(512)

  transpose_bf16<<<dim3(E_/32, E_/32, L_), 256, 0, stream>>>(Wq, Wqkv_b,            E_, E_, (size_t)1536*E_, qscale);
  transpose_bf16<<<dim3(E_/32, E_/32, L_), 256, 0, stream>>>(Wk, Wqkv_b + 512*E_,   E_, E_, (size_t)1536*E_, 1.f);
  transpose_bf16<<<dim3(E_/32, E_/32, L_), 256, 0, stream>>>(Wv, Wqkv_b + 1024*E_,  E_, E_, (size_t)1536*E_, 1.f);
  transpose_bf16<<<dim3(E_/32, E_/32, L_), 256, 0, stream>>>(Wo, Wo_b, E_, E_, (size_t)E_*E_, 1.f);
  transpose_bf16<<<dim3(FF_/32, E_/32, L_), 256, 0, stream>>>(W1, W1_b, E_, FF_, (size_t)E_*FF_, 1.f);
  transpose_bf16<<<dim3(E_/32, FF_/32, L_), 256, 0, stream>>>(W2, W2_b, FF_, E_, (size_t)FF_*E_, 1.f);
  build_bqkv<<<(L_ * 1536 + 255) / 256, 256, 0, stream>>>(bq, bk, bv, bqkv, qscale);
  build_maskbits<<<B_ * 32, 64, 0, stream>>>(mask, bmw);

  embed_kernel<<<NTOK, 256, 0, stream>>>(seq, W_emb, b_emb, pos, x_f32, x_b);

  dim3 gqkv(1536 / 64, NTOK / 128);
  dim3 g512(E_ / 64, NTOK / 128);
  dim3 gff(FF_ / 128, NTOK / 128);
  for (int i = 0; i < L_; ++i) {
    gemm_tn<64, false, 1><<<gqkv, 256, 0, stream>>>(x_b, Wqkv_b + (size_t)i * 1536 * E_,
                                                    bqkv + i * 1536, nullptr, q_b, k_b, vt_b,
                                                    NTOK, 1536, E_);
    attn_mfma<<<B_ * H_ * (S_ / 64), 256, 0, stream>>>(q_b, k_b, vt_b, bmw, at_b);
    gemm_tn<64, false, 0><<<g512, 256, 0, stream>>>(at_b, Wo_b + (size_t)i * E_ * E_, bo + i * E_,
                                                    proj_f32, nullptr, nullptr, nullptr,
                                                    NTOK, E_, E_);
    ln_kernel<<<NTOK / 4, 256, 0, stream>>>(proj_f32, x_f32, ln1g + i * E_, ln1b + i * E_,
                                            x_f32, x_b);
    gemm_tn<128, true, 0><<<gff, 256, 0, stream>>>(x_b, W1_b + (size_t)i * E_ * FF_, b1 + i * FF_,
                                                   nullptr, ffn_b, nullptr, nullptr,
                                                   NTOK, FF_, E_);
    gemm_tn<64, false, 0><<<g512, 256, 0, stream>>>(ffn_b, W2_b + (size_t)i * FF_ * E_, b2 + i * E_,
                                                    proj_f32, nullptr, nullptr, nullptr,
                                                    NTOK, E_, FF_);
    float* xdst = (i == L_ - 1) ? outp : x_f32;
    ln_kernel<<<NTOK / 4, 256, 0, stream>>>(proj_f32, x_f32, ln2g + i * E_, ln2b + i * E_,
                                            xdst, x_b);
  }
}

// Round 11
// 685.709 us; speedup vs baseline: 6.5024x; 1.0102x over previous
//
#include <hip/hip_runtime.h>
#include <hip/hip_bf16.h>

#define B_ 2
#define S_ 2048
#define F_ 64
#define E_ 512
#define H_ 8
#define L_ 4
#define FF_ 2048
#define NTOK (B_*S_)
#define DH 64

typedef __attribute__((ext_vector_type(8))) short bf16x8;
typedef __attribute__((ext_vector_type(4))) float f32x4;

typedef const __attribute__((address_space(1))) void* gptr_t;
typedef __attribute__((address_space(3))) void* lptr_t;

__device__ __forceinline__ float b2f(unsigned short u) {
  union { unsigned int i; float f; } x; x.i = ((unsigned int)u) << 16; return x.f;
}
__device__ __forceinline__ unsigned short f2b(float f) {
  union { float f; unsigned int i; } x; x.f = f;
  unsigned int r = x.i + 0x7fffu + ((x.i >> 16) & 1u);
  return (unsigned short)(r >> 16);
}

// ---------------- tiled transpose + f32->bf16 (+scale): W[z][K][N] -> Wt[z][N][K] ----------------
__global__ __launch_bounds__(256)
void transpose_bf16(const float* __restrict__ W, unsigned short* __restrict__ Wt,
                    int K, int N, size_t zstride, float scale) {
  __shared__ unsigned short tile[32][33];
  const float* Wz = W + (size_t)blockIdx.z * K * N;
  unsigned short* Wtz = Wt + (size_t)blockIdx.z * zstride;
  const int n0 = blockIdx.x * 32, k0 = blockIdx.y * 32;
  const int tx = threadIdx.x & 31, ty = threadIdx.x >> 5;
#pragma unroll
  for (int i = 0; i < 4; ++i)
    tile[tx][ty + i * 8] = f2b(Wz[(size_t)(k0 + ty + i * 8) * N + n0 + tx] * scale);
  __syncthreads();
#pragma unroll
  for (int i = 0; i < 4; ++i)
    Wtz[(size_t)(n0 + ty + i * 8) * K + k0 + tx] = tile[ty + i * 8][tx];
}

// ---------------- concat qkv bias (qscale folded into q part) ----------------
__global__ __launch_bounds__(256)
void build_bqkv(const float* __restrict__ bq, const float* __restrict__ bk,
                const float* __restrict__ bv, float* __restrict__ out, float qs) {
  int i = blockIdx.x * 256 + threadIdx.x;
  if (i >= L_ * 1536) return;
  int l = i / 1536, c = i - l * 1536;
  float v;
  if (c < 512) v = bq[l * 512 + c] * qs;
  else if (c < 1024) v = bk[l * 512 + c - 512];
  else v = bv[l * 512 + c - 1024];
  out[i] = v;
}

// ---------------- mask -> per-64-key-tile u64 bitmask ----------------
__global__ __launch_bounds__(64)
void build_maskbits(const int* __restrict__ mask, unsigned long long* __restrict__ bm) {
  unsigned long long v = __ballot(mask[blockIdx.x * 64 + threadIdx.x] != 0);
  if (threadIdx.x == 0) bm[blockIdx.x] = v;
}

// ---------------- embedding: x = seq @ W_emb + b + pos ----------------
__global__ __launch_bounds__(256)
void embed_kernel(const float* __restrict__ seq, const float* __restrict__ W,
                  const float* __restrict__ be, const float* __restrict__ pe,
                  float* __restrict__ xf, unsigned short* __restrict__ xb) {
  const int n = blockIdx.x;
  const int s = n & (S_ - 1);
  __shared__ float srow[F_];
  if (threadIdx.x < F_) srow[threadIdx.x] = seq[(size_t)n * F_ + threadIdx.x];
  __syncthreads();
  for (int e = threadIdx.x; e < E_; e += 256) {
    float acc = be[e] + pe[(size_t)s * E_ + e];
#pragma unroll 8
    for (int f = 0; f < F_; ++f) acc = fmaf(srow[f], W[(size_t)f * E_ + e], acc);
    xf[(size_t)n * E_ + e] = acc;
    xb[(size_t)n * E_ + e] = f2b(acc);
  }
}

// ---------------- bf16 MFMA GEMM, A[M,K] @ Bt^T + bias (Bt is [N][K]) ----------------
// Staging: global_load_lds width=16, DOUBLE-BUFFERED prefetch — per K-step:
//   barrier (retire tile-k loads, flown during step k-1) -> issue tile k+1 -> compute tile k.
// Linear LDS, frag b128 reads cover contiguous 1024B blocks -> conflict-free.
// MODE 0: Cf (f32), Cb (bf16), Ct (bf16 transposed) — any may be null.
// MODE 1 (fused QKV, N=1536): col<512 -> Cb (q), col<1024 -> Cb2 (k), else Ct (v transposed).
template<int BN, bool RELU, int MODE>
__global__ __launch_bounds__(256)
void gemm_tn(const unsigned short* __restrict__ A, const unsigned short* __restrict__ Bt,
             const float* __restrict__ bias,
             float* __restrict__ Cf, unsigned short* __restrict__ Cb,
             unsigned short* __restrict__ Cb2, unsigned short* __restrict__ Ct,
             int M, int N, int K) {
  constexpr int BM = 128, BK = 32;
  constexpr int FN = BN / 32;   // fragment cols per wave (2-wide wave grid)
  constexpr int WN = BN / 2;    // wave col extent
  __shared__ unsigned short Alds[2][BM * BK];
  __shared__ unsigned short Blds[2][BN * BK];
  const int t = threadIdx.x;
  const int wid = t >> 6, lane = t & 63;
  const int wr = wid >> 1, wc = wid & 1;
  const int rowBase = blockIdx.y * BM;
  const int colBase = blockIdx.x * BN;

  f32x4 acc[4][FN];
#pragma unroll
  for (int i = 0; i < 4; ++i)
#pragma unroll
    for (int j = 0; j < FN; ++j) acc[i][j] = (f32x4){0.f, 0.f, 0.f, 0.f};

  const int lr = lane & 15;
  const int g8 = (lane >> 4) * 8;

  // staging source (per lane): 16-row chunks, lane covers row sr, 16B chunk sc
  const int sr = lane >> 2;          // 0..15
  const int sc = (lane & 3) * 8;     // bf16 units
  const unsigned short* Ab0 = A + (size_t)(rowBase + wid * 32 + sr) * K + sc;
  const unsigned short* Ab1 = Ab0 + (size_t)16 * K;
  const unsigned short* Bb0;
  const unsigned short* Bb1;
  if (FN == 2) {
    Bb0 = Bt + (size_t)(colBase + wid * 16 + sr) * K + sc;
    Bb1 = nullptr;
  } else {
    Bb0 = Bt + (size_t)(colBase + wid * 32 + sr) * K + sc;
    Bb1 = Bb0 + (size_t)16 * K;
  }

  auto stage = [&](int buf, int k0) {
    __builtin_amdgcn_global_load_lds((gptr_t)(Ab0 + k0), (lptr_t)&Alds[buf][wid * 1024], 16, 0, 0);
    __builtin_amdgcn_global_load_lds((gptr_t)(Ab1 + k0), (lptr_t)&Alds[buf][wid * 1024 + 512], 16, 0, 0);
    if (FN == 2) {
      __builtin_amdgcn_global_load_lds((gptr_t)(Bb0 + k0), (lptr_t)&Blds[buf][wid * 512], 16, 0, 0);
    } else {
      __builtin_amdgcn_global_load_lds((gptr_t)(Bb0 + k0), (lptr_t)&Blds[buf][wid * 1024], 16, 0, 0);
      __builtin_amdgcn_global_load_lds((gptr_t)(Bb1 + k0), (lptr_t)&Blds[buf][wid * 1024 + 512], 16, 0, 0);
    }
  };

  // prologue: stage tile 0 into buffer 0
  stage(0, 0);

  int cur = 0;
  for (int k0 = 0; k0 < K; k0 += BK) {
    __syncthreads();                 // retire loads of tile k (issued last step)
    if (k0 + BK < K) stage(cur ^ 1, k0 + BK);   // prefetch next tile (flies under compute)

    bf16x8 af[4];
#pragma unroll
    for (int fm = 0; fm < 4; ++fm)
      af[fm] = *(const bf16x8*)&Alds[cur][(wr * 64 + fm * 16 + lr) * 32 + g8];
#pragma unroll
    for (int fn = 0; fn < FN; ++fn) {
      bf16x8 bfr = *(const bf16x8*)&Blds[cur][(wc * WN + fn * 16 + lr) * 32 + g8];
#pragma unroll
      for (int fm = 0; fm < 4; ++fm)
        acc[fm][fn] = __builtin_amdgcn_mfma_f32_16x16x32_bf16(af[fm], bfr, acc[fm][fn], 0, 0, 0);
    }
    cur ^= 1;
  }

#pragma unroll
  for (int fm = 0; fm < 4; ++fm) {
#pragma unroll
    for (int fn = 0; fn < FN; ++fn) {
      int col = colBase + wc * WN + fn * 16 + lr;
      float bz = bias[col];
      int row0 = rowBase + wr * 64 + fm * 16 + (lane >> 4) * 4;
      float vv[4];
#pragma unroll
      for (int j = 0; j < 4; ++j) {
        float v = acc[fm][fn][j] + bz;
        if (RELU) v = fmaxf(v, 0.f);
        vv[j] = v;
      }
      if (MODE == 1) {
        int sel = col >> 9, lcol = col & 511;
        if (sel == 0) {
#pragma unroll
          for (int j = 0; j < 4; ++j) Cb[(size_t)(row0 + j) * E_ + lcol] = f2b(vv[j]);
        } else if (sel == 1) {
#pragma unroll
          for (int j = 0; j < 4; ++j) Cb2[(size_t)(row0 + j) * E_ + lcol] = f2b(vv[j]);
        } else {
          uint2 pk;
          pk.x = (unsigned)f2b(vv[0]) | ((unsigned)f2b(vv[1]) << 16);
          pk.y = (unsigned)f2b(vv[2]) | ((unsigned)f2b(vv[3]) << 16);
          *(uint2*)&Ct[(size_t)lcol * M + row0] = pk;
        }
      } else {
        if (Cf) {
#pragma unroll
          for (int j = 0; j < 4; ++j) Cf[(size_t)(row0 + j) * N + col] = vv[j];
        }
        if (Cb) {
#pragma unroll
          for (int j = 0; j < 4; ++j) Cb[(size_t)(row0 + j) * N + col] = f2b(vv[j]);
        }
        if (Ct) {
          uint2 pk;
          pk.x = (unsigned)f2b(vv[0]) | ((unsigned)f2b(vv[1]) << 16);
          pk.y = (unsigned)f2b(vv[2]) | ((unsigned)f2b(vv[3]) << 16);
          *(uint2*)&Ct[(size_t)col * M + row0] = pk;
        }
      }
    }
  }
}

// ---------------- MFMA flash attention, LDS-staged K/V (double-buffered) ----------------
__global__ __launch_bounds__(256, 2)
void attn_mfma(const unsigned short* __restrict__ qg, const unsigned short* __restrict__ kg,
               const unsigned short* __restrict__ vt, const unsigned long long* __restrict__ bm,
               unsigned short* __restrict__ outg) {
  __shared__ unsigned short Kl[2][64][64];
  __shared__ unsigned short Vl[2][64][64];
  __shared__ unsigned short plds[4][16][72];
  const int t = threadIdx.x;
  const int wid = t >> 6, lane = t & 63;
  const int g = lane >> 4, lr = lane & 15;
  // XCD-aware swizzle: blocks on one XCD share (b,h) -> K/V stays L2-resident
  const int bid = blockIdx.x;
  const int xcd = bid & 7, idx = bid >> 3;
  const int bh = xcd * 2 + (idx >> 5);   // 0..15
  const int qt = idx & 31;
  const int h = bh & 7, b = bh >> 3;
  const int bS = b * S_;
  const int qrow = bS + qt * 64 + wid * 16;
  const int hd = h * DH;

  const int srow = t >> 3;            // 0..31
  const int scol = (t & 7) * 8;       // ushort offset, 16B chunks
  const int ssw = scol ^ ((srow & 7) << 3);   // swizzled col
  const unsigned short* ksrc = kg + (size_t)bS * E_ + hd;
  const unsigned short* vsrc = vt + (size_t)hd * NTOK + bS;
  const unsigned long long* bmb = bm + b * 32;

  bf16x8 aq0, aq1;
  {
    const unsigned short* qp = qg + (size_t)(qrow + lr) * E_ + hd + g * 8;
    aq0 = *(const bf16x8*)qp;
    aq1 = *(const bf16x8*)(qp + 32);
  }

  f32x4 O[4];
#pragma unroll
  for (int dt = 0; dt < 4; ++dt) O[dt] = (f32x4){0.f, 0.f, 0.f, 0.f};
  float lp[4] = {0.f, 0.f, 0.f, 0.f};

  // prologue: stage tile 0 into buffer 0
  {
    uint4 a = *(const uint4*)&ksrc[(size_t)srow * E_ + scol];
    uint4 c = *(const uint4*)&ksrc[(size_t)(32 + srow) * E_ + scol];
    uint4 d = *(const uint4*)&vsrc[(size_t)srow * NTOK + scol];
    uint4 e = *(const uint4*)&vsrc[(size_t)(srow + 32) * NTOK + scol];
    *(uint4*)&Kl[0][srow][ssw] = a;
    *(uint4*)&Kl[0][srow + 32][ssw] = c;
    *(uint4*)&Vl[0][srow][ssw] = d;
    *(uint4*)&Vl[0][srow + 32][ssw] = e;
  }
  __syncthreads();

  int cur = 0;
#pragma unroll 2
  for (int kt = 0; kt < 32; ++kt) {
    uint4 nk0, nk1, nv0, nv1;
    const int nkb = (kt + 1) * 64;
    if (kt < 31) {
      nk0 = *(const uint4*)&ksrc[(size_t)(nkb + srow) * E_ + scol];
      nk1 = *(const uint4*)&ksrc[(size_t)(nkb + 32 + srow) * E_ + scol];
      nv0 = *(const uint4*)&vsrc[(size_t)srow * NTOK + nkb + scol];
      nv1 = *(const uint4*)&vsrc[(size_t)(srow + 32) * NTOK + nkb + scol];
    }
    const unsigned long long bmv = bmb[kt];
    f32x4 s_[4];
#pragma unroll
    for (int t16 = 0; t16 < 4; ++t16) {
      const int row = t16 * 16 + lr;
      const int sw = (row & 7) << 3;
      bf16x8 b0 = *(const bf16x8*)&Kl[cur][row][(g * 8) ^ sw];
      bf16x8 b1 = *(const bf16x8*)&Kl[cur][row][(32 + g * 8) ^ sw];
      f32x4 z = (f32x4){0.f, 0.f, 0.f, 0.f};
      z = __builtin_amdgcn_mfma_f32_16x16x32_bf16(aq0, b0, z, 0, 0, 0);
      z = __builtin_amdgcn_mfma_f32_16x16x32_bf16(aq1, b1, z, 0, 0, 0);
      s_[t16] = z;
    }
    float p_[4][4];
#pragma unroll
    for (int t16 = 0; t16 < 4; ++t16)
#pragma unroll
      for (int j = 0; j < 4; ++j) p_[t16][j] = __expf(fminf(s_[t16][j], 45.f));
    if (bmv != ~0ull) {
#pragma unroll
      for (int t16 = 0; t16 < 4; ++t16)
        if (!((bmv >> (t16 * 16 + lr)) & 1)) {
#pragma unroll
          for (int j = 0; j < 4; ++j) p_[t16][j] = 0.f;
        }
    }
#pragma unroll
    for (int j = 0; j < 4; ++j)
      lp[j] += (p_[0][j] + p_[1][j]) + (p_[2][j] + p_[3][j]);
#pragma unroll
    for (int t16 = 0; t16 < 4; ++t16)
#pragma unroll
      for (int j = 0; j < 4; ++j)
        plds[wid][g * 4 + j][t16 * 16 + lr] = f2b(p_[t16][j]);
    asm volatile("s_waitcnt lgkmcnt(0)" ::: "memory");
    __builtin_amdgcn_sched_barrier(0);
    bf16x8 pa0 = *(const bf16x8*)&plds[wid][lr][g * 8];
    bf16x8 pa1 = *(const bf16x8*)&plds[wid][lr][32 + g * 8];
#pragma unroll
    for (int dt = 0; dt < 4; ++dt) {
      const int row = dt * 16 + lr;
      const int sw = (row & 7) << 3;
      bf16x8 v0 = *(const bf16x8*)&Vl[cur][row][(g * 8) ^ sw];
      bf16x8 v1 = *(const bf16x8*)&Vl[cur][row][(32 + g * 8) ^ sw];
      O[dt] = __builtin_amdgcn_mfma_f32_16x16x32_bf16(pa0, v0, O[dt], 0, 0, 0);
      O[dt] = __builtin_amdgcn_mfma_f32_16x16x32_bf16(pa1, v1, O[dt], 0, 0, 0);
    }
    if (kt < 31) {
      *(uint4*)&Kl[cur ^ 1][srow][ssw] = nk0;
      *(uint4*)&Kl[cur ^ 1][srow + 32][ssw] = nk1;
      *(uint4*)&Vl[cur ^ 1][srow][ssw] = nv0;
      *(uint4*)&Vl[cur ^ 1][srow + 32][ssw] = nv1;
    }
    __syncthreads();
    cur ^= 1;
  }

#pragma unroll
  for (int j = 0; j < 4; ++j) {
    float v = lp[j];
    v += __shfl_xor(v, 1);
    v += __shfl_xor(v, 2);
    v += __shfl_xor(v, 4);
    v += __shfl_xor(v, 8);
    lp[j] = 1.f / v;
  }
#pragma unroll
  for (int dt = 0; dt < 4; ++dt)
#pragma unroll
    for (int j = 0; j < 4; ++j)
      outg[(size_t)(qrow + g * 4 + j) * E_ + hd + dt * 16 + lr] = f2b(O[dt][j] * lp[j]);
}

// ---------------- fused residual + layernorm (+ bf16 recast) ----------------
__global__ __launch_bounds__(256)
void ln_kernel(const float* __restrict__ y, const float* __restrict__ xin,
               const float* __restrict__ g, const float* __restrict__ bb,
               float* __restrict__ xf, unsigned short* __restrict__ xb) {
  const int t = threadIdx.x, wid = t >> 6, lane = t & 63;
  const int row = blockIdx.x * 4 + wid;
  const float* yr = y + (size_t)row * E_;
  const float* xr = xin + (size_t)row * E_;
  float vals[8];
  float s = 0.f;
#pragma unroll
  for (int j = 0; j < 8; ++j) {
    float val = yr[lane * 8 + j] + xr[lane * 8 + j];
    vals[j] = val; s += val;
  }
#pragma unroll
  for (int off = 32; off > 0; off >>= 1) s += __shfl_xor(s, off);
  float mean = s * (1.f / 512.f);
  float vv = 0.f;
#pragma unroll
  for (int j = 0; j < 8; ++j) { float d = vals[j] - mean; vv += d * d; }
#pragma unroll
  for (int off = 32; off > 0; off >>= 1) vv += __shfl_xor(vv, off);
  float inv = rsqrtf(vv * (1.f / 512.f) + 1e-5f);
#pragma unroll
  for (int j = 0; j < 8; ++j) {
    int col = lane * 8 + j;
    float r = (vals[j] - mean) * inv * g[col] + bb[col];
    xf[(size_t)row * E_ + col] = r;
    xb[(size_t)row * E_ + col] = f2b(r);
  }
}

extern "C" void kernel_launch(void* const* d_in, const int* in_sizes, int n_in,
                              void* d_out, int out_size, void* d_ws, size_t ws_size,
                              hipStream_t stream) {
  const float* seq   = (const float*)d_in[0];
  const int*   mask  = (const int*)d_in[1];
  const float* W_emb = (const float*)d_in[2];
  const float* b_emb = (const float*)d_in[3];
  const float* pos   = (const float*)d_in[4];
  const float* Wq = (const float*)d_in[5];  const float* bq = (const float*)d_in[6];
  const float* Wk = (const float*)d_in[7];  const float* bk = (const float*)d_in[8];
  const float* Wv = (const float*)d_in[9];  const float* bv = (const float*)d_in[10];
  const float* Wo = (const float*)d_in[11]; const float* bo = (const float*)d_in[12];
  const float* ln1g = (const float*)d_in[13]; const float* ln1b = (const float*)d_in[14];
  const float* ln2g = (const float*)d_in[15]; const float* ln2b = (const float*)d_in[16];
  const float* W1 = (const float*)d_in[17]; const float* b1 = (const float*)d_in[18];
  const float* W2 = (const float*)d_in[19]; const float* b2 = (const float*)d_in[20];
  float* outp = (float*)d_out;

  char* w = (char*)d_ws;
  float*  x_f32    = (float*)w;           w += (size_t)NTOK * E_ * 4;
  float*  proj_f32 = (float*)w;           w += (size_t)NTOK * E_ * 4;
  float*  bqkv     = (float*)w;           w += (size_t)L_ * 1536 * 4;
  unsigned long long* bmw = (unsigned long long*)w; w += (size_t)B_ * 32 * 8;
  unsigned short* x_b    = (unsigned short*)w; w += (size_t)NTOK * E_ * 2;
  unsigned short* q_b    = (unsigned short*)w; w += (size_t)NTOK * E_ * 2;
  unsigned short* k_b    = (unsigned short*)w; w += (size_t)NTOK * E_ * 2;
  unsigned short* vt_b   = (unsigned short*)w; w += (size_t)NTOK * E_ * 2;
  unsigned short* at_b   = (unsigned short*)w; w += (size_t)NTOK * E_ * 2;
  unsigned short* ffn_b  = (unsigned short*)w; w += (size_t)NTOK * FF_ * 2;
  unsigned short* Wqkv_b = (unsigned short*)w; w += (size_t)L_ * 1536 * E_ * 2;
  unsigned short* Wo_b   = (unsigned short*)w; w += (size_t)L_ * E_ * E_ * 2;
  unsigned short* W1_b   = (unsigned short*)w; w += (size_t)L_ * E_ * FF_ * 2;
  unsigned short* W2_b   = (unsigned short*)w; w += (size_t)L_ * FF_ * E_ * 2;

  const float qscale = 0.04419417382415922f;  // 1/sqrt(512)

  transpose_bf16<<<dim3(E_/32, E_/32, L_), 256, 0, stream>>>(Wq, Wqkv_b,            E_, E_, (size_t)1536*E_, qscale);
  transpose_bf16<<<dim3(E_/32, E_/32, L_), 256, 0, stream>>>(Wk, Wqkv_b + 512*E_,   E_, E_, (size_t)1536*E_, 1.f);
  transpose_bf16<<<dim3(E_/32, E_/32, L_), 256, 0, stream>>>(Wv, Wqkv_b + 1024*E_,  E_, E_, (size_t)1536*E_, 1.f);
  transpose_bf16<<<dim3(E_/32, E_/32, L_), 256, 0, stream>>>(Wo, Wo_b, E_, E_, (size_t)E_*E_, 1.f);
  transpose_bf16<<<dim3(FF_/32, E_/32, L_), 256, 0, stream>>>(W1, W1_b, E_, FF_, (size_t)E_*FF_, 1.f);
  transpose_bf16<<<dim3(E_/32, FF_/32, L_), 256, 0, stream>>>(W2, W2_b, FF_, E_, (size_t)FF_*E_, 1.f);
  build_bqkv<<<(L_ * 1536 + 255) / 256, 256, 0, stream>>>(bq, bk, bv, bqkv, qscale);
  build_maskbits<<<B_ * 32, 64, 0, stream>>>(mask, bmw);

  embed_kernel<<<NTOK, 256, 0, stream>>>(seq, W_emb, b_emb, pos, x_f32, x_b);

  dim3 gqkv(1536 / 64, NTOK / 128);
  dim3 g512(E_ / 64, NTOK / 128);
  dim3 gff(FF_ / 128, NTOK / 128);
  for (int i = 0; i < L_; ++i) {
    gemm_tn<64, false, 1><<<gqkv, 256, 0, stream>>>(x_b, Wqkv_b + (size_t)i * 1536 * E_,
                                                    bqkv + i * 1536, nullptr, q_b, k_b, vt_b,
                                                    NTOK, 1536, E_);
    attn_mfma<<<B_ * H_ * (S_ / 64), 256, 0, stream>>>(q_b, k_b, vt_b, bmw, at_b);
    gemm_tn<64, false, 0><<<g512, 256, 0, stream>>>(at_b, Wo_b + (size_t)i * E_ * E_, bo + i * E_,
                                                    proj_f32, nullptr, nullptr, nullptr,
                                                    NTOK, E_, E_);
    ln_kernel<<<NTOK / 4, 256, 0, stream>>>(proj_f32, x_f32, ln1g + i * E_, ln1b + i * E_,
                                            x_f32, x_b);
    gemm_tn<128, true, 0><<<gff, 256, 0, stream>>>(x_b, W1_b + (size_t)i * E_ * FF_, b1 + i * FF_,
                                                   nullptr, ffn_b, nullptr, nullptr,
                                                   NTOK, FF_, E_);
    gemm_tn<64, false, 0><<<g512, 256, 0, stream>>>(ffn_b, W2_b + (size_t)i * FF_ * E_, b2 + i * E_,
                                                    proj_f32, nullptr, nullptr, nullptr,
                                                    NTOK, E_, FF_);
    float* xdst = (i == L_ - 1) ? outp : x_f32;
    ln_kernel<<<NTOK / 4, 256, 0, stream>>>(proj_f32, x_f32, ln2g + i * E_, ln2b + i * E_,
                                            xdst, x_b);
  }
}